// Round 15
// baseline (508.581 us; speedup 1.0000x reference)
//
#include <hip/hip_runtime.h>
#include <math.h>

#define NTREE 512
#define NNODE 48
#define HD 256
#define LD 64
#define VOC 800
#define TSTEP 94
#define NFWD 47

typedef __attribute__((ext_vector_type(8))) short s8v;   // 8 bf16 (4 VGPRs)
typedef __attribute__((ext_vector_type(4))) float f4v;   // 4 fp32 acc

// fast device transcendentals (v_exp_f32 + v_rcp_f32), GRU-only
__device__ __forceinline__ float sigm_f(float x) {
    return __builtin_amdgcn_rcpf(1.f + __expf(-x));
}
__device__ __forceinline__ float tanh_f(float x) {
    return 1.f - 2.f * __builtin_amdgcn_rcpf(1.f + __expf(2.f * x));
}

__device__ __forceinline__ float bfu(unsigned short u) {
    union { unsigned int i; float f; } c; c.i = ((unsigned int)u) << 16; return c.f;
}
__device__ __forceinline__ unsigned short f2bf(float f) {
    union { float f; unsigned int u; } c; c.f = f;
    return (unsigned short)((c.u + 0x7fffu + ((c.u >> 16) & 1u)) >> 16);
}
__device__ __forceinline__ s8v frag(const unsigned short* p) {
    union { int4 i; s8v v; } u; u.i = *(const int4*)p; return u.v;
}
__device__ __forceinline__ s8v zfrag() {
    union { int4 i; s8v v; } u; u.i = make_int4(0, 0, 0, 0); return u.v;
}
// LDS-only barrier: global ops (hsb stores, gathers) stay in flight.
__device__ __forceinline__ void bar_lgkm() {
    asm volatile("s_waitcnt lgkmcnt(0)\n\ts_barrier" ::: "memory");
}

// ---------------------------------------------------------------------------
// Fused prep: [0,4) init acc; [4,772) tcvt3; [772,2084) tcvtQ;
// [2084,3012) cvtE (928 exact); [3012,3112) xproj (100 blocks x 8 vocab rows).
// ---------------------------------------------------------------------------
#define PV 8
__global__ __launch_bounds__(256) void prep_misc(
    const float* __restrict__ Wz, const float* __restrict__ bz,
    const float* __restrict__ Wh, const float* __restrict__ bh,
    const float* __restrict__ Wr, const float* __restrict__ br,
    const float* __restrict__ Ur,
    const float* __restrict__ Ww, const float* __restrict__ Wow,
    const float* __restrict__ Uw,
    const float* __restrict__ emb, const float* __restrict__ tv,
    unsigned short* __restrict__ WzT, unsigned short* __restrict__ WhT,
    unsigned short* __restrict__ UrT,
    unsigned short* __restrict__ W1T, unsigned short* __restrict__ WoT,
    unsigned short* __restrict__ UwT,
    unsigned short* __restrict__ embB, unsigned short* __restrict__ tvB,
    float* __restrict__ xzT, float* __restrict__ xhT, float* __restrict__ xrT,
    float* __restrict__ acc)
{
    __shared__ float embL[PV][HD];
    int b = blockIdx.x;
    if (b < 4) {
        acc[b * 256 + threadIdx.x] = 0.f;
    } else if (b < 772) {
        int bb = b - 4;
        const int which = bb >> 8, n = bb & 255, k = threadIdx.x;
        const float* src = (which == 0) ? (Wz + HD * HD) : (which == 1) ? (Wh + HD * HD) : Ur;
        unsigned short* dst = (which == 0) ? WzT : (which == 1) ? WhT : UrT;
        dst[n * HD + k] = f2bf(src[k * HD + n]);
    } else if (b < 2084) {
        int bb = b - 772;
        if (bb < 256) {
            for (int k = threadIdx.x; k < 320; k += 256)
                W1T[bb * 320 + k] = f2bf(Ww[k * 256 + bb]);
        } else if (bb < 1056) {
            int n = bb - 256;
            WoT[n * 256 + threadIdx.x] = f2bf(Wow[threadIdx.x * VOC + n]);
        } else {
            int n = bb - 1056;
            for (int k = threadIdx.x; k < 576; k += 256)
                UwT[n * 576 + k] = f2bf(Uw[k * 256 + n]);
        }
    } else if (b < 3012) {
        int idx = (b - 2084) * 256 + threadIdx.x;
        if (idx < VOC * HD) embB[idx] = f2bf(emb[idx]);
        else {
            int i2 = idx - VOC * HD;
            if (i2 < NTREE * LD) tvB[i2] = f2bf(tv[i2]);
        }
    } else {
        // ---- xproj: xz/xh/xr for 8 vocab rows ----
        const int j = threadIdx.x;
        const int v0 = (b - 3012) * PV;
        for (int r = 0; r < PV; ++r) embL[r][j] = emb[(v0 + r) * HD + j];
        __syncthreads();

        float az[PV], ah[PV], ar[PV];
#pragma unroll
        for (int r = 0; r < PV; ++r) { az[r] = bz[j]; ah[r] = bh[j]; ar[r] = br[j]; }
        for (int i = 0; i < HD; i += 4) {
            float wz0 = Wz[(i + 0) * HD + j], wz1 = Wz[(i + 1) * HD + j];
            float wz2 = Wz[(i + 2) * HD + j], wz3 = Wz[(i + 3) * HD + j];
            float wh0 = Wh[(i + 0) * HD + j], wh1 = Wh[(i + 1) * HD + j];
            float wh2 = Wh[(i + 2) * HD + j], wh3 = Wh[(i + 3) * HD + j];
            float wr0 = Wr[(i + 0) * HD + j], wr1 = Wr[(i + 1) * HD + j];
            float wr2 = Wr[(i + 2) * HD + j], wr3 = Wr[(i + 3) * HD + j];
#pragma unroll
            for (int r = 0; r < PV; ++r) {
                float4 e = *(const float4*)&embL[r][i];
                az[r] += e.x * wz0 + e.y * wz1 + e.z * wz2 + e.w * wz3;
                ah[r] += e.x * wh0 + e.y * wh1 + e.z * wh2 + e.w * wh3;
                ar[r] += e.x * wr0 + e.y * wr1 + e.z * wr2 + e.w * wr3;
            }
        }
#pragma unroll
        for (int r = 0; r < PV; ++r) {
            xzT[(v0 + r) * HD + j] = az[r];
            xhT[(v0 + r) * HD + j] = ah[r];
            xrT[(v0 + r) * HD + j] = ar[r];
        }
    }
}

// ---------------------------------------------------------------------------
// GRU v10 body (champion, ~200 us). UNCHANGED from R14.
// ---------------------------------------------------------------------------
__global__ __launch_bounds__(512, 2) void gru10(
    const int* __restrict__ wid,
    const float* __restrict__ xzT, const float* __restrict__ xhT,
    const float* __restrict__ xrT,
    const unsigned short* __restrict__ WzT, const unsigned short* __restrict__ WhT,
    const unsigned short* __restrict__ UrT,
    unsigned short* __restrict__ hsb)
{
    __shared__ unsigned short urL[16 * 8 * 64 * 8];   // 128 KB [tile][kt][lane][8]
    __shared__ unsigned short mBL[2][2][HD], armBL[2][2][HD];
    __shared__ int widL[2][NNODE];

    const int tid = threadIdx.x;
    const int wave = tid >> 6, lane = tid & 63;
    const int lq = lane >> 4, ln = lane & 15;
    const int b0 = blockIdx.x * 2;
    const int T0 = 2 * wave, T1 = T0 + 1;
    const int ftree = lane >> 5;
    const int fcol  = wave * 32 + (lane & 31);
    const int srcl  = lane & 15;
    const bool hi16 = (lane & 16) != 0;
    const bool hi32 = (lane & 32) != 0;

    if (tid < 2 * NNODE) widL[tid / NNODE][tid % NNODE] =
        wid[(b0 + tid / NNODE) * NNODE + (tid % NNODE)];

#pragma unroll
    for (int s = 0; s < 16; ++s) {
        *(int4*)&urL[((s * 8 + wave) * 64 + lane) * 8] =
            *(const int4*)&UrT[(s * 16 + ln) * HD + wave * 32 + lq * 8];
    }

    s8v wz0[8], wz1[8], wh0[8], wh1[8];
#pragma unroll
    for (int kt = 0; kt < 8; ++kt) {
        const int ko = kt * 32 + lq * 8;
        wz0[kt] = frag(&WzT[(T0 * 16 + ln) * HD + ko]);
        wz1[kt] = frag(&WzT[(T1 * 16 + ln) * HD + ko]);
        wh0[kt] = frag(&WhT[(T0 * 16 + ln) * HD + ko]);
        wh1[kt] = frag(&WhT[(T1 * 16 + ln) * HD + ko]);
    }
    __syncthreads();   // widL + urL visible

    float cxz, cxh, cxr, chsp = 0.f, me = 0.f;
    float nxz = 0.f, nxh = 0.f, nxr = 0.f, nhsp = 0.f;
    {
        const int ws = widL[ftree][0], wd = widL[ftree][1];
        cxz = xzT[ws * HD + fcol];
        cxh = xhT[ws * HD + fcol];
        cxr = xrT[wd * HD + fcol];
    }

#pragma unroll 2
    for (int t = 0; t < TSTEP; ++t) {
        const int par = t & 1, nxt = par ^ 1;
        const bool fwd = t < NFWD;
        const bool hp = (t != 0) && (t != NFWD);

        // ---- prefetch for t+1 ----
        {
            if (t == NFWD)
                chsp = bfu(hsb[((NFWD - 2) * NTREE + b0 + ftree) * HD + fcol]);
            const int tn = t + 1;
            if (tn < TSTEP) {
                const bool fwdn = tn < NFWD;
                const int un = TSTEP - tn;
                const int srcn = fwdn ? tn : un;
                const int dstn = fwdn ? (tn + 1) : (un - 1);
                const int ws = widL[ftree][srcn], wd = widL[ftree][dstn];
                nxz = xzT[ws * HD + fcol];
                nxh = xhT[ws * HD + fcol];
                nxr = xrT[wd * HD + fcol];
                nhsp = 0.f;
                if (tn > NFWD && dstn > 0)
                    nhsp = bfu(hsb[((dstn - 1) * NTREE + b0 + ftree) * HD + fcol]);
            }
        }

        // ---- phase A MFMA + shuffle redistribute: az, ah ----
        float az = 0.f, ah = 0.f;
        if (hp) {
            f4v cz0 = (f4v){0.f,0.f,0.f,0.f}, cz1 = cz0, ch0 = cz0, ch1 = cz0;
#pragma unroll
            for (int kt = 0; kt < 8; ++kt) {
                const int ko = kt * 32 + lq * 8;
                s8v am = (ln < 2) ? frag(&mBL[par][ln][ko]) : zfrag();
                s8v aa = (ln < 2) ? frag(&armBL[par][ln][ko]) : zfrag();
                cz0 = __builtin_amdgcn_mfma_f32_16x16x32_bf16(am, wz0[kt], cz0, 0, 0, 0);
                cz1 = __builtin_amdgcn_mfma_f32_16x16x32_bf16(am, wz1[kt], cz1, 0, 0, 0);
                ch0 = __builtin_amdgcn_mfma_f32_16x16x32_bf16(aa, wh0[kt], ch0, 0, 0, 0);
                ch1 = __builtin_amdgcn_mfma_f32_16x16x32_bf16(aa, wh1[kt], ch1, 0, 0, 0);
            }
            float a00 = __shfl(cz0[0], srcl), a01 = __shfl(cz0[1], srcl);
            float a10 = __shfl(cz1[0], srcl), a11 = __shfl(cz1[1], srcl);
            az = hi16 ? (hi32 ? a11 : a10) : (hi32 ? a01 : a00);
            float h00 = __shfl(ch0[0], srcl), h01 = __shfl(ch0[1], srcl);
            float h10 = __shfl(ch1[0], srcl), h11 = __shfl(ch1[1], srcl);
            ah = hi16 ? (hi32 ? h11 : h10) : (hi32 ? h01 : h00);
        }

        // ---- finalize A ----
        {
            float azv = cxz, ahv = cxh, sold = 0.f;
            if (hp) { azv += az; ahv += ah; sold = me; }
            float z = sigm_f(azv), mt = tanh_f(ahv);
            me = sold + z * (mt - sold);
            float hv = fwd ? me : (me + chsp);
            hsb[(t * NTREE + b0 + ftree) * HD + fcol] = f2bf(hv);
            mBL[nxt][ftree][fcol] = f2bf(me);
        }
        bar_lgkm();

        // ---- phase B MFMA + shuffle: ar = m_e @ Ur ----
        {
            f4v cr0 = (f4v){0.f,0.f,0.f,0.f}, cr1 = cr0;
#pragma unroll
            for (int kt = 0; kt < 8; ++kt) {
                const int ko = kt * 32 + lq * 8;
                s8v a = (ln < 2) ? frag(&mBL[nxt][ln][ko]) : zfrag();
                s8v b0f = frag(&urL[((T0 * 8 + kt) * 64 + lane) * 8]);
                s8v b1f = frag(&urL[((T1 * 8 + kt) * 64 + lane) * 8]);
                cr0 = __builtin_amdgcn_mfma_f32_16x16x32_bf16(a, b0f, cr0, 0, 0, 0);
                cr1 = __builtin_amdgcn_mfma_f32_16x16x32_bf16(a, b1f, cr1, 0, 0, 0);
            }
            float r00 = __shfl(cr0[0], srcl), r01 = __shfl(cr0[1], srcl);
            float r10 = __shfl(cr1[0], srcl), r11 = __shfl(cr1[1], srcl);
            float ar = hi16 ? (hi32 ? r11 : r10) : (hi32 ? r01 : r00);
            float r = sigm_f(cxr + ar);
            armBL[nxt][ftree][fcol] = f2bf(r * me);
            cxz = nxz; cxh = nxh; cxr = nxr; chsp = nhsp;
        }
        bar_lgkm();
    }
}

// ---------------------------------------------------------------------------
// Fused heads: [0,768) = Q, [768,2288) = P. Staged LDS A-inputs; B-fragments
// double-buffered in registers (1 tile ahead) so MFMAs overlap L2 loads.
// ---------------------------------------------------------------------------
#define QG 32
#define PG 32
struct QSmem {
    unsigned short X1L[QG][328];
    unsigned short hidL[QG][264];
    int tgts[QG];
    float wred[4][QG][4];
};
struct PSmem {
    unsigned short XL[PG][584];
    int widL[PG];
    float wredp[4][PG];
};

__global__ __launch_bounds__(256) void heads(
    const int* __restrict__ wid,
    const unsigned short* __restrict__ tvB,
    const unsigned short* __restrict__ embB,
    const unsigned short* __restrict__ hsb,
    const unsigned short* __restrict__ W1T,
    const unsigned short* __restrict__ WoT,
    const unsigned short* __restrict__ UwT,
    const float* __restrict__ Wb, const float* __restrict__ Wob,
    const float* __restrict__ Ub,
    const float* __restrict__ Usw, const float* __restrict__ Usb,
    float* __restrict__ acc)
{
    __shared__ __align__(16) char smem[sizeof(QSmem) > sizeof(PSmem) ? sizeof(QSmem) : sizeof(PSmem)];
    const int tid = threadIdx.x;
    const int wave = tid >> 6, lane = tid & 63;
    const int lq = lane >> 4, ln = lane & 15;

    if (blockIdx.x < 768) {
        // ================= Q head =================
        QSmem& S = *(QSmem*)smem;
        const int trow = blockIdx.x >> 4;
        const int b0 = (blockIdx.x & 15) * QG;

        if (tid < QG) S.tgts[tid] = wid[(b0 + tid) * NNODE + trow];
        if (trow == 0) {
            int4 z = make_int4(0, 0, 0, 0);
            for (int idx = tid; idx < QG * 32; idx += 256) {
                int m = idx >> 5, c = idx & 31;
                *(int4*)&S.X1L[m][c * 8] = z;
            }
        } else {
            const unsigned short* hrow = hsb + (size_t)(trow - 1) * NTREE * HD;
            for (int idx = tid; idx < QG * 32; idx += 256) {
                int m = idx >> 5, c = idx & 31;
                *(int4*)&S.X1L[m][c * 8] = *(const int4*)&hrow[(b0 + m) * HD + c * 8];
            }
        }
        for (int idx = tid; idx < QG * 8; idx += 256) {
            int m = idx >> 3, c = idx & 7;
            *(int4*)&S.X1L[m][256 + c * 8] = *(const int4*)&tvB[(b0 + m) * LD + c * 8];
        }
        __syncthreads();

        // stage 1 with B double-buffer (prefetch kt+1 during kt's MFMAs)
        f4v acc1[2][4];
#pragma unroll
        for (int mt = 0; mt < 2; ++mt)
#pragma unroll
            for (int nt = 0; nt < 4; ++nt) acc1[mt][nt] = (f4v){0.f, 0.f, 0.f, 0.f};
        s8v bq[2][4];
#pragma unroll
        for (int nt = 0; nt < 4; ++nt)
            bq[0][nt] = frag(&W1T[(wave * 64 + nt * 16 + ln) * 320 + lq * 8]);
#pragma unroll
        for (int kt = 0; kt < 10; ++kt) {
            const int cur = kt & 1, nx = cur ^ 1;
            if (kt < 9) {
#pragma unroll
                for (int nt = 0; nt < 4; ++nt)
                    bq[nx][nt] = frag(&W1T[(wave * 64 + nt * 16 + ln) * 320 + (kt + 1) * 32 + lq * 8]);
            }
            s8v a0 = frag(&S.X1L[ln][kt * 32 + lq * 8]);
            s8v a1 = frag(&S.X1L[16 + ln][kt * 32 + lq * 8]);
#pragma unroll
            for (int nt = 0; nt < 4; ++nt) {
                acc1[0][nt] = __builtin_amdgcn_mfma_f32_16x16x32_bf16(a0, bq[cur][nt], acc1[0][nt], 0, 0, 0);
                acc1[1][nt] = __builtin_amdgcn_mfma_f32_16x16x32_bf16(a1, bq[cur][nt], acc1[1][nt], 0, 0, 0);
            }
        }
#pragma unroll
        for (int nt = 0; nt < 4; ++nt) {
            int col = wave * 64 + nt * 16 + ln;
            float wb = Wb[col];
#pragma unroll
            for (int mt = 0; mt < 2; ++mt)
#pragma unroll
                for (int r = 0; r < 4; ++r)
                    S.hidL[mt * 16 + lq * 4 + r][col] = f2bf(fmaxf(acc1[mt][nt][r] + wb, 0.f));
        }
        __syncthreads();

        // stage 2: ha in regs; B (WoT rows) double-buffered one nt-tile ahead
        s8v ha0[8], ha1[8];
#pragma unroll
        for (int kt = 0; kt < 8; ++kt) {
            ha0[kt] = frag(&S.hidL[ln][kt * 32 + lq * 8]);
            ha1[kt] = frag(&S.hidL[16 + ln][kt * 32 + lq * 8]);
        }

        int rt[2][4];
#pragma unroll
        for (int mt = 0; mt < 2; ++mt)
#pragma unroll
            for (int r = 0; r < 4; ++r) rt[mt][r] = S.tgts[mt * 16 + lq * 4 + r];
        float mx[2][4], ls[2][4], tg[2][4]; int am[2][4];
#pragma unroll
        for (int mt = 0; mt < 2; ++mt)
#pragma unroll
            for (int r = 0; r < 4; ++r) { mx[mt][r] = -1e30f; ls[mt][r] = 0.f; tg[mt][r] = 0.f; am[mt][r] = 1 << 30; }

        s8v bo[2][8];
        {
            const unsigned short* w0 = WoT + (wave * 16 + ln) * 256;
#pragma unroll
            for (int kt = 0; kt < 8; ++kt) bo[0][kt] = frag(&w0[kt * 32 + lq * 8]);
        }
        int pb = 0;
        for (int nt = wave; nt < 50; nt += 4) {
            const int cur = pb, nx = pb ^ 1; pb ^= 1;
            if (nt + 4 < 50) {
                const unsigned short* wn = WoT + ((nt + 4) * 16 + ln) * 256;
#pragma unroll
                for (int kt = 0; kt < 8; ++kt) bo[nx][kt] = frag(&wn[kt * 32 + lq * 8]);
            }
            int n = nt * 16 + ln;
            f4v a2[2];
            a2[0] = (f4v){0.f, 0.f, 0.f, 0.f}; a2[1] = (f4v){0.f, 0.f, 0.f, 0.f};
#pragma unroll
            for (int kt = 0; kt < 8; ++kt) {
                a2[0] = __builtin_amdgcn_mfma_f32_16x16x32_bf16(ha0[kt], bo[cur][kt], a2[0], 0, 0, 0);
                a2[1] = __builtin_amdgcn_mfma_f32_16x16x32_bf16(ha1[kt], bo[cur][kt], a2[1], 0, 0, 0);
            }
            float bias = Wob[n];
#pragma unroll
            for (int mt = 0; mt < 2; ++mt)
#pragma unroll
                for (int r = 0; r < 4; ++r) {
                    float v = a2[mt][r] + bias;
                    if (n == rt[mt][r]) tg[mt][r] = v;
                    float d = v - mx[mt][r];
                    float e = __expf(-fabsf(d));
                    bool newmax = d > 0.f;
                    ls[mt][r] = fmaf(ls[mt][r], newmax ? e : 1.f, newmax ? 1.f : e);
                    if (newmax) { mx[mt][r] = v; am[mt][r] = n; }
                }
        }

#pragma unroll
        for (int s = 1; s < 16; s <<= 1) {
#pragma unroll
            for (int mt = 0; mt < 2; ++mt)
#pragma unroll
                for (int r = 0; r < 4; ++r) {
                    float mo = __shfl_xor(mx[mt][r], s);
                    float lo = __shfl_xor(ls[mt][r], s);
                    int   ao = __shfl_xor(am[mt][r], s);
                    float to = __shfl_xor(tg[mt][r], s);
                    tg[mt][r] += to;
                    float nm = fmaxf(mx[mt][r], mo);
                    ls[mt][r] = ls[mt][r] * __expf(mx[mt][r] - nm) + lo * __expf(mo - nm);
                    if (mo > mx[mt][r] || (mo == mx[mt][r] && ao < am[mt][r])) am[mt][r] = ao;
                    mx[mt][r] = nm;
                }
        }
        if (ln == 0) {
#pragma unroll
            for (int mt = 0; mt < 2; ++mt)
#pragma unroll
                for (int r = 0; r < 4; ++r) {
                    int row = mt * 16 + lq * 4 + r;
                    S.wred[wave][row][0] = mx[mt][r];
                    S.wred[wave][row][1] = ls[mt][r];
                    S.wred[wave][row][2] = __int_as_float(am[mt][r]);
                    S.wred[wave][row][3] = tg[mt][r];
                }
        }
        __syncthreads();

        float lossv = 0.f, corrv = 0.f;
        if (tid < QG) {
            float m_ = -1e30f, l_ = 0.f, t_ = 0.f; int a_ = 1 << 30;
#pragma unroll
            for (int w = 0; w < 4; ++w) {
                float mo = S.wred[w][tid][0], lo = S.wred[w][tid][1], to = S.wred[w][tid][3];
                int ao = __float_as_int(S.wred[w][tid][2]);
                t_ += to;
                float nm = fmaxf(m_, mo);
                l_ = l_ * __expf(m_ - nm) + lo * __expf(mo - nm);
                if (mo > m_ || (mo == m_ && ao < a_)) a_ = ao;
                m_ = nm;
            }
            lossv = m_ + logf(l_) - t_;
            corrv = (a_ == S.tgts[tid]) ? 1.f : 0.f;
        }
        if (wave == 0) {
            for (int s = 32; s; s >>= 1) {
                lossv += __shfl_down(lossv, s);
                corrv += __shfl_down(corrv, s);
            }
            if (tid == 0) {
                int slot = blockIdx.x & 255;
                atomicAdd(&acc[0 * 256 + slot], lossv);
                atomicAdd(&acc[2 * 256 + slot], corrv);
            }
        }
    } else {
        // ================= P head =================
        PSmem& S = *(PSmem*)smem;
        const int pb_ = blockIdx.x - 768;
        const int trow = pb_ >> 4;
        const int b0 = (pb_ & 15) * PG;
        const int node = (trow == 0) ? 0 : ((trow <= NFWD) ? trow : (TSTEP - trow));

        if (tid < PG) S.widL[tid] = wid[(b0 + tid) * NNODE + node];
        __syncthreads();

        for (int idx = tid; idx < PG * 32; idx += 256) {
            int m = idx >> 5, c = idx & 31;
            *(int4*)&S.XL[m][c * 8] = *(const int4*)&embB[S.widL[m] * HD + c * 8];
        }
        if (trow == 0) {
            int4 z = make_int4(0, 0, 0, 0);
            for (int idx = tid; idx < PG * 32; idx += 256) {
                int m = idx >> 5, c = idx & 31;
                *(int4*)&S.XL[m][256 + c * 8] = z;
            }
        } else {
            const unsigned short* hrow = hsb + (size_t)(trow - 1) * NTREE * HD;
            for (int idx = tid; idx < PG * 32; idx += 256) {
                int m = idx >> 5, c = idx & 31;
                *(int4*)&S.XL[m][256 + c * 8] = *(const int4*)&hrow[(b0 + m) * HD + c * 8];
            }
        }
        for (int idx = tid; idx < PG * 8; idx += 256) {
            int m = idx >> 3, c = idx & 7;
            *(int4*)&S.XL[m][512 + c * 8] = *(const int4*)&tvB[(b0 + m) * LD + c * 8];
        }
        __syncthreads();

        f4v a1[2][4];
#pragma unroll
        for (int mt = 0; mt < 2; ++mt)
#pragma unroll
            for (int nt = 0; nt < 4; ++nt) a1[mt][nt] = (f4v){0.f, 0.f, 0.f, 0.f};
        s8v bp[2][4];
#pragma unroll
        for (int nt = 0; nt < 4; ++nt)
            bp[0][nt] = frag(&UwT[(wave * 64 + nt * 16 + ln) * 576 + lq * 8]);
        for (int kt = 0; kt < 18; ++kt) {
            const int cur = kt & 1, nx = cur ^ 1;
            if (kt < 17) {
#pragma unroll
                for (int nt = 0; nt < 4; ++nt)
                    bp[nx][nt] = frag(&UwT[(wave * 64 + nt * 16 + ln) * 576 + (kt + 1) * 32 + lq * 8]);
            }
            s8v a0 = frag(&S.XL[ln][kt * 32 + lq * 8]);
            s8v am_ = frag(&S.XL[16 + ln][kt * 32 + lq * 8]);
#pragma unroll
            for (int nt = 0; nt < 4; ++nt) {
                a1[0][nt] = __builtin_amdgcn_mfma_f32_16x16x32_bf16(a0, bp[cur][nt], a1[0][nt], 0, 0, 0);
                a1[1][nt] = __builtin_amdgcn_mfma_f32_16x16x32_bf16(am_, bp[cur][nt], a1[1][nt], 0, 0, 0);
            }
        }
        float part[2][4] = {{0, 0, 0, 0}, {0, 0, 0, 0}};
#pragma unroll
        for (int nt = 0; nt < 4; ++nt) {
            int n = wave * 64 + nt * 16 + ln;
            float ub = Ub[n], us = Usw[n];
#pragma unroll
            for (int mt = 0; mt < 2; ++mt)
#pragma unroll
                for (int r = 0; r < 4; ++r)
                    part[mt][r] += fmaxf(a1[mt][nt][r] + ub, 0.f) * us;
        }
#pragma unroll
        for (int s = 1; s < 16; s <<= 1) {
#pragma unroll
            for (int mt = 0; mt < 2; ++mt)
#pragma unroll
                for (int r = 0; r < 4; ++r)
                    part[mt][r] += __shfl_xor(part[mt][r], s);
        }
        if (ln == 0) {
#pragma unroll
            for (int mt = 0; mt < 2; ++mt)
#pragma unroll
                for (int r = 0; r < 4; ++r)
                    S.wredp[wave][mt * 16 + lq * 4 + r] = part[mt][r];
        }
        __syncthreads();

        float lossv = 0.f, corrv = 0.f;
        if (tid < PG) {
            float p = S.wredp[0][tid] + S.wredp[1][tid] + S.wredp[2][tid] + S.wredp[3][tid] + Usb[0];
            float tgt = (trow < NFWD) ? 1.f : 0.f;
            lossv = fmaxf(p, 0.f) - p * tgt + log1pf(expf(-fabsf(p)));
            corrv = (((p > 0.f) ? 1 : 0) == ((trow < NFWD) ? 1 : 0)) ? 1.f : 0.f;
        }
        if (wave == 0) {
            for (int s = 32; s; s >>= 1) {
                lossv += __shfl_down(lossv, s);
                corrv += __shfl_down(corrv, s);
            }
            if (tid == 0) {
                int slot = blockIdx.x & 255;
                atomicAdd(&acc[1 * 256 + slot], lossv);
                atomicAdd(&acc[3 * 256 + slot], corrv);
            }
        }
    }
}

__global__ void fin_kernel(const float* __restrict__ acc, float* __restrict__ out) {
    const int tid = threadIdx.x;
    const int c = tid >> 6, lane = tid & 63;
    float v = 0.f;
    for (int i = lane; i < 256; i += 64) v += acc[c * 256 + i];
    for (int s = 32; s; s >>= 1) v += __shfl_down(v, s);
    if (lane == 0) {
        const float sc[4] = {1.f / 512.f, 1.f / 512.f, 1.f / 24576.f, 1.f / 48640.f};
        out[c] = v * sc[c];
    }
}

extern "C" void kernel_launch(void* const* d_in, const int* in_sizes, int n_in,
                              void* d_out, int out_size, void* d_ws, size_t ws_size,
                              hipStream_t stream) {
    const int*   wid  = (const int*)  d_in[12];
    const float* tv   = (const float*)d_in[13];
    const float* emb  = (const float*)d_in[14];
    const float* Wz   = (const float*)d_in[15];
    const float* bz   = (const float*)d_in[16];
    const float* Wr   = (const float*)d_in[17];
    const float* Ur   = (const float*)d_in[18];
    const float* br   = (const float*)d_in[19];
    const float* Wh   = (const float*)d_in[20];
    const float* bh   = (const float*)d_in[21];
    const float* Ww   = (const float*)d_in[22];
    const float* Wb   = (const float*)d_in[23];
    const float* Uw   = (const float*)d_in[24];
    const float* Ubias= (const float*)d_in[25];
    const float* Wow  = (const float*)d_in[26];
    const float* Wob  = (const float*)d_in[27];
    const float* Usw  = (const float*)d_in[28];
    const float* Usb  = (const float*)d_in[29];

    char* w = (char*)d_ws;
    float* accb = (float*)w;                                 // 4 KB
    float* xzT  = (float*)(w + 4096);                        // 800*256 f32
    float* xhT  = (float*)(w + 823296);
    float* xrT  = (float*)(w + 1642496);
    unsigned short* WzT2 = (unsigned short*)(w + 2461696);   // [256 n][256 k] bf16
    unsigned short* WhT2 = (unsigned short*)(w + 2592768);
    unsigned short* UrT2 = (unsigned short*)(w + 2723840);
    unsigned short* hsb  = (unsigned short*)(w + 2854912);   // 94*512*256 bf16
    unsigned short* W1T  = (unsigned short*)(w + 27496448);  // [256][320]
    unsigned short* WoT  = (unsigned short*)(w + 27660288);  // [800][256]
    unsigned short* UwT  = (unsigned short*)(w + 28069888);  // [256][576]
    unsigned short* embB = (unsigned short*)(w + 28364800);  // [800][256]
    unsigned short* tvB  = (unsigned short*)(w + 28774400);  // [512][64]

    prep_misc<<<3112, 256, 0, stream>>>(Wz, bz, Wh, bh, Wr, br, Ur, Ww, Wow, Uw,
                                        emb, tv, WzT2, WhT2, UrT2, W1T, WoT, UwT,
                                        embB, tvB, xzT, xhT, xrT, accb);
    gru10<<<NTREE / 2, 512, 0, stream>>>(wid, xzT, xhT, xrT, WzT2, WhT2, UrT2, hsb);
    heads<<<768 + 1520, 256, 0, stream>>>(wid, tvB, embB, hsb, W1T, WoT, UwT,
                                          Wb, Wob, Ubias, Usw, Usb, accb);
    fin_kernel<<<1, 256, 0, stream>>>(accb, (float*)d_out);
}

// Round 16
// 448.639 us; speedup vs baseline: 1.1336x; 1.1336x over previous
//
#include <hip/hip_runtime.h>
#include <math.h>

#define NTREE 512
#define NNODE 48
#define HD 256
#define LD 64
#define VOC 800
#define TSTEP 94
#define NFWD 47

typedef __attribute__((ext_vector_type(8))) short s8v;   // 8 bf16 (4 VGPRs)
typedef __attribute__((ext_vector_type(4))) float f4v;   // 4 fp32 acc

// fast device transcendentals (v_exp_f32 + v_rcp_f32), GRU-only
__device__ __forceinline__ float sigm_f(float x) {
    return __builtin_amdgcn_rcpf(1.f + __expf(-x));
}
__device__ __forceinline__ float tanh_f(float x) {
    return 1.f - 2.f * __builtin_amdgcn_rcpf(1.f + __expf(2.f * x));
}

__device__ __forceinline__ float bfu(unsigned short u) {
    union { unsigned int i; float f; } c; c.i = ((unsigned int)u) << 16; return c.f;
}
__device__ __forceinline__ unsigned short f2bf(float f) {
    union { float f; unsigned int u; } c; c.f = f;
    return (unsigned short)((c.u + 0x7fffu + ((c.u >> 16) & 1u)) >> 16);
}
__device__ __forceinline__ s8v frag(const unsigned short* p) {
    union { int4 i; s8v v; } u; u.i = *(const int4*)p; return u.v;
}
__device__ __forceinline__ s8v zfrag() {
    union { int4 i; s8v v; } u; u.i = make_int4(0, 0, 0, 0); return u.v;
}
// LDS-only barrier: global ops (hsb stores, gathers) stay in flight.
__device__ __forceinline__ void bar_lgkm() {
    asm volatile("s_waitcnt lgkmcnt(0)\n\ts_barrier" ::: "memory");
}

// ---------------------------------------------------------------------------
// Precompute x-projections for all 800 vocab words (biases folded in).
// ---------------------------------------------------------------------------
#define PV 8
__global__ __launch_bounds__(256) void prep_xproj(
    const float* __restrict__ emb,
    const float* __restrict__ Wz, const float* __restrict__ bz,
    const float* __restrict__ Wh, const float* __restrict__ bh,
    const float* __restrict__ Wr, const float* __restrict__ br,
    float* __restrict__ xzT, float* __restrict__ xhT, float* __restrict__ xrT)
{
    __shared__ float embL[PV][HD];
    const int j = threadIdx.x;
    const int v0 = blockIdx.x * PV;
    for (int r = 0; r < PV; ++r) embL[r][j] = emb[(v0 + r) * HD + j];
    __syncthreads();

    float az[PV], ah[PV], ar[PV];
#pragma unroll
    for (int r = 0; r < PV; ++r) { az[r] = bz[j]; ah[r] = bh[j]; ar[r] = br[j]; }
    for (int i = 0; i < HD; i += 4) {
        float wz0 = Wz[(i + 0) * HD + j], wz1 = Wz[(i + 1) * HD + j];
        float wz2 = Wz[(i + 2) * HD + j], wz3 = Wz[(i + 3) * HD + j];
        float wh0 = Wh[(i + 0) * HD + j], wh1 = Wh[(i + 1) * HD + j];
        float wh2 = Wh[(i + 2) * HD + j], wh3 = Wh[(i + 3) * HD + j];
        float wr0 = Wr[(i + 0) * HD + j], wr1 = Wr[(i + 1) * HD + j];
        float wr2 = Wr[(i + 2) * HD + j], wr3 = Wr[(i + 3) * HD + j];
#pragma unroll
        for (int r = 0; r < PV; ++r) {
            float4 e = *(const float4*)&embL[r][i];
            az[r] += e.x * wz0 + e.y * wz1 + e.z * wz2 + e.w * wz3;
            ah[r] += e.x * wh0 + e.y * wh1 + e.z * wh2 + e.w * wh3;
            ar[r] += e.x * wr0 + e.y * wr1 + e.z * wr2 + e.w * wr3;
        }
    }
#pragma unroll
    for (int r = 0; r < PV; ++r) {
        xzT[(v0 + r) * HD + j] = az[r];
        xhT[(v0 + r) * HD + j] = ah[r];
        xrT[(v0 + r) * HD + j] = ar[r];
    }
}

// ---------------------------------------------------------------------------
// Fused misc prep: [0,4) init acc; [4,772) tcvt3; [772,2084) tcvtQ;
// [2084, 3012) cvtE  (928 blocks = ceil((800*256 + 512*64)/256) -- exact).
// ---------------------------------------------------------------------------
__global__ __launch_bounds__(256) void prep_misc(
    const float* __restrict__ Wz, const float* __restrict__ Wh,
    const float* __restrict__ Ur,
    const float* __restrict__ Ww, const float* __restrict__ Wow,
    const float* __restrict__ Uw,
    const float* __restrict__ emb, const float* __restrict__ tv,
    unsigned short* __restrict__ WzT, unsigned short* __restrict__ WhT,
    unsigned short* __restrict__ UrT,
    unsigned short* __restrict__ W1T, unsigned short* __restrict__ WoT,
    unsigned short* __restrict__ UwT,
    unsigned short* __restrict__ embB, unsigned short* __restrict__ tvB,
    float* __restrict__ acc)
{
    int b = blockIdx.x;
    if (b < 4) {
        acc[b * 256 + threadIdx.x] = 0.f;
    } else if (b < 772) {
        int bb = b - 4;
        const int which = bb >> 8, n = bb & 255, k = threadIdx.x;
        const float* src = (which == 0) ? (Wz + HD * HD) : (which == 1) ? (Wh + HD * HD) : Ur;
        unsigned short* dst = (which == 0) ? WzT : (which == 1) ? WhT : UrT;
        dst[n * HD + k] = f2bf(src[k * HD + n]);
    } else if (b < 2084) {
        int bb = b - 772;
        if (bb < 256) {
            for (int k = threadIdx.x; k < 320; k += 256)
                W1T[bb * 320 + k] = f2bf(Ww[k * 256 + bb]);
        } else if (bb < 1056) {
            int n = bb - 256;
            WoT[n * 256 + threadIdx.x] = f2bf(Wow[threadIdx.x * VOC + n]);
        } else {
            int n = bb - 1056;
            for (int k = threadIdx.x; k < 576; k += 256)
                UwT[n * 576 + k] = f2bf(Uw[k * 256 + n]);
        }
    } else {
        int idx = (b - 2084) * 256 + threadIdx.x;
        if (idx < VOC * HD) embB[idx] = f2bf(emb[idx]);
        else {
            int i2 = idx - VOC * HD;
            if (i2 < NTREE * LD) tvB[i2] = f2bf(tv[i2]);
        }
    }
}

// ---------------------------------------------------------------------------
// GRU v10 body (champion, ~200 us). 256 wgs x 512 thr, 2 trees/wg.
// Wz/Wh tiles in regs; Ur in LDS fragment-contiguous. Shuffle finalize,
// 2 lgkm-only barriers/step.
// ---------------------------------------------------------------------------
__global__ __launch_bounds__(512, 2) void gru10(
    const int* __restrict__ wid,
    const float* __restrict__ xzT, const float* __restrict__ xhT,
    const float* __restrict__ xrT,
    const unsigned short* __restrict__ WzT, const unsigned short* __restrict__ WhT,
    const unsigned short* __restrict__ UrT,
    unsigned short* __restrict__ hsb)
{
    __shared__ unsigned short urL[16 * 8 * 64 * 8];   // 128 KB [tile][kt][lane][8]
    __shared__ unsigned short mBL[2][2][HD], armBL[2][2][HD];
    __shared__ int widL[2][NNODE];

    const int tid = threadIdx.x;
    const int wave = tid >> 6, lane = tid & 63;
    const int lq = lane >> 4, ln = lane & 15;
    const int b0 = blockIdx.x * 2;
    const int T0 = 2 * wave, T1 = T0 + 1;
    const int ftree = lane >> 5;
    const int fcol  = wave * 32 + (lane & 31);
    const int srcl  = lane & 15;
    const bool hi16 = (lane & 16) != 0;
    const bool hi32 = (lane & 32) != 0;

    if (tid < 2 * NNODE) widL[tid / NNODE][tid % NNODE] =
        wid[(b0 + tid / NNODE) * NNODE + (tid % NNODE)];

#pragma unroll
    for (int s = 0; s < 16; ++s) {
        *(int4*)&urL[((s * 8 + wave) * 64 + lane) * 8] =
            *(const int4*)&UrT[(s * 16 + ln) * HD + wave * 32 + lq * 8];
    }

    s8v wz0[8], wz1[8], wh0[8], wh1[8];
#pragma unroll
    for (int kt = 0; kt < 8; ++kt) {
        const int ko = kt * 32 + lq * 8;
        wz0[kt] = frag(&WzT[(T0 * 16 + ln) * HD + ko]);
        wz1[kt] = frag(&WzT[(T1 * 16 + ln) * HD + ko]);
        wh0[kt] = frag(&WhT[(T0 * 16 + ln) * HD + ko]);
        wh1[kt] = frag(&WhT[(T1 * 16 + ln) * HD + ko]);
    }
    __syncthreads();   // widL + urL visible

    float cxz, cxh, cxr, chsp = 0.f, me = 0.f;
    float nxz = 0.f, nxh = 0.f, nxr = 0.f, nhsp = 0.f;
    {
        const int ws = widL[ftree][0], wd = widL[ftree][1];
        cxz = xzT[ws * HD + fcol];
        cxh = xhT[ws * HD + fcol];
        cxr = xrT[wd * HD + fcol];
    }

#pragma unroll 2
    for (int t = 0; t < TSTEP; ++t) {
        const int par = t & 1, nxt = par ^ 1;
        const bool fwd = t < NFWD;
        const bool hp = (t != 0) && (t != NFWD);

        // ---- prefetch for t+1 ----
        {
            if (t == NFWD)
                chsp = bfu(hsb[((NFWD - 2) * NTREE + b0 + ftree) * HD + fcol]);
            const int tn = t + 1;
            if (tn < TSTEP) {
                const bool fwdn = tn < NFWD;
                const int un = TSTEP - tn;
                const int srcn = fwdn ? tn : un;
                const int dstn = fwdn ? (tn + 1) : (un - 1);
                const int ws = widL[ftree][srcn], wd = widL[ftree][dstn];
                nxz = xzT[ws * HD + fcol];
                nxh = xhT[ws * HD + fcol];
                nxr = xrT[wd * HD + fcol];
                nhsp = 0.f;
                if (tn > NFWD && dstn > 0)
                    nhsp = bfu(hsb[((dstn - 1) * NTREE + b0 + ftree) * HD + fcol]);
            }
        }

        // ---- phase A MFMA + shuffle redistribute: az, ah ----
        float az = 0.f, ah = 0.f;
        if (hp) {
            f4v cz0 = (f4v){0.f,0.f,0.f,0.f}, cz1 = cz0, ch0 = cz0, ch1 = cz0;
#pragma unroll
            for (int kt = 0; kt < 8; ++kt) {
                const int ko = kt * 32 + lq * 8;
                s8v am = (ln < 2) ? frag(&mBL[par][ln][ko]) : zfrag();
                s8v aa = (ln < 2) ? frag(&armBL[par][ln][ko]) : zfrag();
                cz0 = __builtin_amdgcn_mfma_f32_16x16x32_bf16(am, wz0[kt], cz0, 0, 0, 0);
                cz1 = __builtin_amdgcn_mfma_f32_16x16x32_bf16(am, wz1[kt], cz1, 0, 0, 0);
                ch0 = __builtin_amdgcn_mfma_f32_16x16x32_bf16(aa, wh0[kt], ch0, 0, 0, 0);
                ch1 = __builtin_amdgcn_mfma_f32_16x16x32_bf16(aa, wh1[kt], ch1, 0, 0, 0);
            }
            float a00 = __shfl(cz0[0], srcl), a01 = __shfl(cz0[1], srcl);
            float a10 = __shfl(cz1[0], srcl), a11 = __shfl(cz1[1], srcl);
            az = hi16 ? (hi32 ? a11 : a10) : (hi32 ? a01 : a00);
            float h00 = __shfl(ch0[0], srcl), h01 = __shfl(ch0[1], srcl);
            float h10 = __shfl(ch1[0], srcl), h11 = __shfl(ch1[1], srcl);
            ah = hi16 ? (hi32 ? h11 : h10) : (hi32 ? h01 : h00);
        }

        // ---- finalize A ----
        {
            float azv = cxz, ahv = cxh, sold = 0.f;
            if (hp) { azv += az; ahv += ah; sold = me; }
            float z = sigm_f(azv), mt = tanh_f(ahv);
            me = sold + z * (mt - sold);
            float hv = fwd ? me : (me + chsp);
            hsb[(t * NTREE + b0 + ftree) * HD + fcol] = f2bf(hv);
            mBL[nxt][ftree][fcol] = f2bf(me);
        }
        bar_lgkm();

        // ---- phase B MFMA + shuffle: ar = m_e @ Ur ----
        {
            f4v cr0 = (f4v){0.f,0.f,0.f,0.f}, cr1 = cr0;
#pragma unroll
            for (int kt = 0; kt < 8; ++kt) {
                const int ko = kt * 32 + lq * 8;
                s8v a = (ln < 2) ? frag(&mBL[nxt][ln][ko]) : zfrag();
                s8v b0f = frag(&urL[((T0 * 8 + kt) * 64 + lane) * 8]);
                s8v b1f = frag(&urL[((T1 * 8 + kt) * 64 + lane) * 8]);
                cr0 = __builtin_amdgcn_mfma_f32_16x16x32_bf16(a, b0f, cr0, 0, 0, 0);
                cr1 = __builtin_amdgcn_mfma_f32_16x16x32_bf16(a, b1f, cr1, 0, 0, 0);
            }
            float r00 = __shfl(cr0[0], srcl), r01 = __shfl(cr0[1], srcl);
            float r10 = __shfl(cr1[0], srcl), r11 = __shfl(cr1[1], srcl);
            float ar = hi16 ? (hi32 ? r11 : r10) : (hi32 ? r01 : r00);
            float r = sigm_f(cxr + ar);
            armBL[nxt][ftree][fcol] = f2bf(r * me);
            cxz = nxz; cxh = nxh; cxr = nxr; chsp = nhsp;
        }
        bar_lgkm();
    }
}

// ---------------------------------------------------------------------------
// Fused heads: [0,768) = Q, [768,2288) = P. Staged LDS inputs (R11-proven);
// branchless 1-exp online softmax; stage-2 ha-frags cached in registers.
// ---------------------------------------------------------------------------
#define QG 32
#define PG 32
struct QSmem {
    unsigned short X1L[QG][328];
    unsigned short hidL[QG][264];
    int tgts[QG];
    float wred[4][QG][4];
};
struct PSmem {
    unsigned short XL[PG][584];
    int widL[PG];
    float wredp[4][PG];
};

__global__ __launch_bounds__(256) void heads(
    const int* __restrict__ wid,
    const unsigned short* __restrict__ tvB,
    const unsigned short* __restrict__ embB,
    const unsigned short* __restrict__ hsb,
    const unsigned short* __restrict__ W1T,
    const unsigned short* __restrict__ WoT,
    const unsigned short* __restrict__ UwT,
    const float* __restrict__ Wb, const float* __restrict__ Wob,
    const float* __restrict__ Ub,
    const float* __restrict__ Usw, const float* __restrict__ Usb,
    float* __restrict__ acc)
{
    __shared__ __align__(16) char smem[sizeof(QSmem) > sizeof(PSmem) ? sizeof(QSmem) : sizeof(PSmem)];
    const int tid = threadIdx.x;
    const int wave = tid >> 6, lane = tid & 63;
    const int lq = lane >> 4, ln = lane & 15;

    if (blockIdx.x < 768) {
        // ================= Q head =================
        QSmem& S = *(QSmem*)smem;
        const int trow = blockIdx.x >> 4;
        const int b0 = (blockIdx.x & 15) * QG;

        if (tid < QG) S.tgts[tid] = wid[(b0 + tid) * NNODE + trow];
        if (trow == 0) {
            int4 z = make_int4(0, 0, 0, 0);
            for (int idx = tid; idx < QG * 32; idx += 256) {
                int m = idx >> 5, c = idx & 31;
                *(int4*)&S.X1L[m][c * 8] = z;
            }
        } else {
            const unsigned short* hrow = hsb + (size_t)(trow - 1) * NTREE * HD;
            for (int idx = tid; idx < QG * 32; idx += 256) {
                int m = idx >> 5, c = idx & 31;
                *(int4*)&S.X1L[m][c * 8] = *(const int4*)&hrow[(b0 + m) * HD + c * 8];
            }
        }
        for (int idx = tid; idx < QG * 8; idx += 256) {
            int m = idx >> 3, c = idx & 7;
            *(int4*)&S.X1L[m][256 + c * 8] = *(const int4*)&tvB[(b0 + m) * LD + c * 8];
        }
        __syncthreads();

        f4v acc1[2][4];
#pragma unroll
        for (int mt = 0; mt < 2; ++mt)
#pragma unroll
            for (int nt = 0; nt < 4; ++nt) acc1[mt][nt] = (f4v){0.f, 0.f, 0.f, 0.f};
#pragma unroll
        for (int kt = 0; kt < 10; ++kt) {
            s8v a0 = frag(&S.X1L[ln][kt * 32 + lq * 8]);
            s8v a1 = frag(&S.X1L[16 + ln][kt * 32 + lq * 8]);
#pragma unroll
            for (int nt = 0; nt < 4; ++nt) {
                int n = wave * 64 + nt * 16 + ln;
                s8v b = frag(&W1T[n * 320 + kt * 32 + lq * 8]);
                acc1[0][nt] = __builtin_amdgcn_mfma_f32_16x16x32_bf16(a0, b, acc1[0][nt], 0, 0, 0);
                acc1[1][nt] = __builtin_amdgcn_mfma_f32_16x16x32_bf16(a1, b, acc1[1][nt], 0, 0, 0);
            }
        }
#pragma unroll
        for (int nt = 0; nt < 4; ++nt) {
            int col = wave * 64 + nt * 16 + ln;
            float wb = Wb[col];
#pragma unroll
            for (int mt = 0; mt < 2; ++mt)
#pragma unroll
                for (int r = 0; r < 4; ++r)
                    S.hidL[mt * 16 + lq * 4 + r][col] = f2bf(fmaxf(acc1[mt][nt][r] + wb, 0.f));
        }
        __syncthreads();

        // stage 2: hid A-frags cached in registers (was 13x LDS re-read)
        s8v ha0[8], ha1[8];
#pragma unroll
        for (int kt = 0; kt < 8; ++kt) {
            ha0[kt] = frag(&S.hidL[ln][kt * 32 + lq * 8]);
            ha1[kt] = frag(&S.hidL[16 + ln][kt * 32 + lq * 8]);
        }

        int rt[2][4];
#pragma unroll
        for (int mt = 0; mt < 2; ++mt)
#pragma unroll
            for (int r = 0; r < 4; ++r) rt[mt][r] = S.tgts[mt * 16 + lq * 4 + r];
        float mx[2][4], ls[2][4], tg[2][4]; int am[2][4];
#pragma unroll
        for (int mt = 0; mt < 2; ++mt)
#pragma unroll
            for (int r = 0; r < 4; ++r) { mx[mt][r] = -1e30f; ls[mt][r] = 0.f; tg[mt][r] = 0.f; am[mt][r] = 1 << 30; }

        for (int nt = wave; nt < 50; nt += 4) {
            int n = nt * 16 + ln;
            const unsigned short* wrow = WoT + n * 256;
            f4v a2[2];
            a2[0] = (f4v){0.f, 0.f, 0.f, 0.f}; a2[1] = (f4v){0.f, 0.f, 0.f, 0.f};
#pragma unroll
            for (int kt = 0; kt < 8; ++kt) {
                s8v b = frag(&wrow[kt * 32 + lq * 8]);
                a2[0] = __builtin_amdgcn_mfma_f32_16x16x32_bf16(ha0[kt], b, a2[0], 0, 0, 0);
                a2[1] = __builtin_amdgcn_mfma_f32_16x16x32_bf16(ha1[kt], b, a2[1], 0, 0, 0);
            }
            float bias = Wob[n];
#pragma unroll
            for (int mt = 0; mt < 2; ++mt)
#pragma unroll
                for (int r = 0; r < 4; ++r) {
                    float v = a2[mt][r] + bias;
                    if (n == rt[mt][r]) tg[mt][r] = v;
                    float d = v - mx[mt][r];
                    float e = __expf(-fabsf(d));
                    bool newmax = d > 0.f;
                    ls[mt][r] = fmaf(ls[mt][r], newmax ? e : 1.f, newmax ? 1.f : e);
                    if (newmax) { mx[mt][r] = v; am[mt][r] = n; }
                }
        }

#pragma unroll
        for (int s = 1; s < 16; s <<= 1) {
#pragma unroll
            for (int mt = 0; mt < 2; ++mt)
#pragma unroll
                for (int r = 0; r < 4; ++r) {
                    float mo = __shfl_xor(mx[mt][r], s);
                    float lo = __shfl_xor(ls[mt][r], s);
                    int   ao = __shfl_xor(am[mt][r], s);
                    float to = __shfl_xor(tg[mt][r], s);
                    tg[mt][r] += to;
                    float nm = fmaxf(mx[mt][r], mo);
                    ls[mt][r] = ls[mt][r] * __expf(mx[mt][r] - nm) + lo * __expf(mo - nm);
                    if (mo > mx[mt][r] || (mo == mx[mt][r] && ao < am[mt][r])) am[mt][r] = ao;
                    mx[mt][r] = nm;
                }
        }
        if (ln == 0) {
#pragma unroll
            for (int mt = 0; mt < 2; ++mt)
#pragma unroll
                for (int r = 0; r < 4; ++r) {
                    int row = mt * 16 + lq * 4 + r;
                    S.wred[wave][row][0] = mx[mt][r];
                    S.wred[wave][row][1] = ls[mt][r];
                    S.wred[wave][row][2] = __int_as_float(am[mt][r]);
                    S.wred[wave][row][3] = tg[mt][r];
                }
        }
        __syncthreads();

        float lossv = 0.f, corrv = 0.f;
        if (tid < QG) {
            float m_ = -1e30f, l_ = 0.f, t_ = 0.f; int a_ = 1 << 30;
#pragma unroll
            for (int w = 0; w < 4; ++w) {
                float mo = S.wred[w][tid][0], lo = S.wred[w][tid][1], to = S.wred[w][tid][3];
                int ao = __float_as_int(S.wred[w][tid][2]);
                t_ += to;
                float nm = fmaxf(m_, mo);
                l_ = l_ * __expf(m_ - nm) + lo * __expf(mo - nm);
                if (mo > m_ || (mo == m_ && ao < a_)) a_ = ao;
                m_ = nm;
            }
            lossv = m_ + logf(l_) - t_;
            corrv = (a_ == S.tgts[tid]) ? 1.f : 0.f;
        }
        if (wave == 0) {
            for (int s = 32; s; s >>= 1) {
                lossv += __shfl_down(lossv, s);
                corrv += __shfl_down(corrv, s);
            }
            if (tid == 0) {
                int slot = blockIdx.x & 255;
                atomicAdd(&acc[0 * 256 + slot], lossv);
                atomicAdd(&acc[2 * 256 + slot], corrv);
            }
        }
    } else {
        // ================= P head =================
        PSmem& S = *(PSmem*)smem;
        const int pb = blockIdx.x - 768;
        const int trow = pb >> 4;
        const int b0 = (pb & 15) * PG;
        const int node = (trow == 0) ? 0 : ((trow <= NFWD) ? trow : (TSTEP - trow));

        if (tid < PG) S.widL[tid] = wid[(b0 + tid) * NNODE + node];
        __syncthreads();

        for (int idx = tid; idx < PG * 32; idx += 256) {
            int m = idx >> 5, c = idx & 31;
            *(int4*)&S.XL[m][c * 8] = *(const int4*)&embB[S.widL[m] * HD + c * 8];
        }
        if (trow == 0) {
            int4 z = make_int4(0, 0, 0, 0);
            for (int idx = tid; idx < PG * 32; idx += 256) {
                int m = idx >> 5, c = idx & 31;
                *(int4*)&S.XL[m][256 + c * 8] = z;
            }
        } else {
            const unsigned short* hrow = hsb + (size_t)(trow - 1) * NTREE * HD;
            for (int idx = tid; idx < PG * 32; idx += 256) {
                int m = idx >> 5, c = idx & 31;
                *(int4*)&S.XL[m][256 + c * 8] = *(const int4*)&hrow[(b0 + m) * HD + c * 8];
            }
        }
        for (int idx = tid; idx < PG * 8; idx += 256) {
            int m = idx >> 3, c = idx & 7;
            *(int4*)&S.XL[m][512 + c * 8] = *(const int4*)&tvB[(b0 + m) * LD + c * 8];
        }
        __syncthreads();

        f4v a1[2][4];
#pragma unroll
        for (int mt = 0; mt < 2; ++mt)
#pragma unroll
            for (int nt = 0; nt < 4; ++nt) a1[mt][nt] = (f4v){0.f, 0.f, 0.f, 0.f};
        for (int kt = 0; kt < 18; ++kt) {
            s8v a0 = frag(&S.XL[ln][kt * 32 + lq * 8]);
            s8v am_ = frag(&S.XL[16 + ln][kt * 32 + lq * 8]);
#pragma unroll
            for (int nt = 0; nt < 4; ++nt) {
                int n = wave * 64 + nt * 16 + ln;
                s8v b = frag(&UwT[n * 576 + kt * 32 + lq * 8]);
                a1[0][nt] = __builtin_amdgcn_mfma_f32_16x16x32_bf16(a0, b, a1[0][nt], 0, 0, 0);
                a1[1][nt] = __builtin_amdgcn_mfma_f32_16x16x32_bf16(am_, b, a1[1][nt], 0, 0, 0);
            }
        }
        float part[2][4] = {{0, 0, 0, 0}, {0, 0, 0, 0}};
#pragma unroll
        for (int nt = 0; nt < 4; ++nt) {
            int n = wave * 64 + nt * 16 + ln;
            float ub = Ub[n], us = Usw[n];
#pragma unroll
            for (int mt = 0; mt < 2; ++mt)
#pragma unroll
                for (int r = 0; r < 4; ++r)
                    part[mt][r] += fmaxf(a1[mt][nt][r] + ub, 0.f) * us;
        }
#pragma unroll
        for (int s = 1; s < 16; s <<= 1) {
#pragma unroll
            for (int mt = 0; mt < 2; ++mt)
#pragma unroll
                for (int r = 0; r < 4; ++r)
                    part[mt][r] += __shfl_xor(part[mt][r], s);
        }
        if (ln == 0) {
#pragma unroll
            for (int mt = 0; mt < 2; ++mt)
#pragma unroll
                for (int r = 0; r < 4; ++r)
                    S.wredp[wave][mt * 16 + lq * 4 + r] = part[mt][r];
        }
        __syncthreads();

        float lossv = 0.f, corrv = 0.f;
        if (tid < PG) {
            float p = S.wredp[0][tid] + S.wredp[1][tid] + S.wredp[2][tid] + S.wredp[3][tid] + Usb[0];
            float tgt = (trow < NFWD) ? 1.f : 0.f;
            lossv = fmaxf(p, 0.f) - p * tgt + log1pf(expf(-fabsf(p)));
            corrv = (((p > 0.f) ? 1 : 0) == ((trow < NFWD) ? 1 : 0)) ? 1.f : 0.f;
        }
        if (wave == 0) {
            for (int s = 32; s; s >>= 1) {
                lossv += __shfl_down(lossv, s);
                corrv += __shfl_down(corrv, s);
            }
            if (tid == 0) {
                int slot = blockIdx.x & 255;
                atomicAdd(&acc[1 * 256 + slot], lossv);
                atomicAdd(&acc[3 * 256 + slot], corrv);
            }
        }
    }
}

__global__ void fin_kernel(const float* __restrict__ acc, float* __restrict__ out) {
    const int tid = threadIdx.x;
    const int c = tid >> 6, lane = tid & 63;
    float v = 0.f;
    for (int i = lane; i < 256; i += 64) v += acc[c * 256 + i];
    for (int s = 32; s; s >>= 1) v += __shfl_down(v, s);
    if (lane == 0) {
        const float sc[4] = {1.f / 512.f, 1.f / 512.f, 1.f / 24576.f, 1.f / 48640.f};
        out[c] = v * sc[c];
    }
}

extern "C" void kernel_launch(void* const* d_in, const int* in_sizes, int n_in,
                              void* d_out, int out_size, void* d_ws, size_t ws_size,
                              hipStream_t stream) {
    const int*   wid  = (const int*)  d_in[12];
    const float* tv   = (const float*)d_in[13];
    const float* emb  = (const float*)d_in[14];
    const float* Wz   = (const float*)d_in[15];
    const float* bz   = (const float*)d_in[16];
    const float* Wr   = (const float*)d_in[17];
    const float* Ur   = (const float*)d_in[18];
    const float* br   = (const float*)d_in[19];
    const float* Wh   = (const float*)d_in[20];
    const float* bh   = (const float*)d_in[21];
    const float* Ww   = (const float*)d_in[22];
    const float* Wb   = (const float*)d_in[23];
    const float* Uw   = (const float*)d_in[24];
    const float* Ubias= (const float*)d_in[25];
    const float* Wow  = (const float*)d_in[26];
    const float* Wob  = (const float*)d_in[27];
    const float* Usw  = (const float*)d_in[28];
    const float* Usb  = (const float*)d_in[29];

    char* w = (char*)d_ws;
    float* accb = (float*)w;                                 // 4 KB
    float* xzT  = (float*)(w + 4096);                        // 800*256 f32
    float* xhT  = (float*)(w + 823296);
    float* xrT  = (float*)(w + 1642496);
    unsigned short* WzT2 = (unsigned short*)(w + 2461696);   // [256 n][256 k] bf16
    unsigned short* WhT2 = (unsigned short*)(w + 2592768);
    unsigned short* UrT2 = (unsigned short*)(w + 2723840);
    unsigned short* hsb  = (unsigned short*)(w + 2854912);   // 94*512*256 bf16
    unsigned short* W1T  = (unsigned short*)(w + 27496448);  // [256][320]
    unsigned short* WoT  = (unsigned short*)(w + 27660288);  // [800][256]
    unsigned short* UwT  = (unsigned short*)(w + 28069888);  // [256][576]
    unsigned short* embB = (unsigned short*)(w + 28364800);  // [800][256]
    unsigned short* tvB  = (unsigned short*)(w + 28774400);  // [512][64]

    prep_xproj<<<VOC / PV, 256, 0, stream>>>(emb, Wz, bz, Wh, bh, Wr, br, xzT, xhT, xrT);
    prep_misc<<<3012, 256, 0, stream>>>(Wz, Wh, Ur, Ww, Wow, Uw, emb, tv,
                                        WzT2, WhT2, UrT2, W1T, WoT, UwT,
                                        embB, tvB, accb);
    gru10<<<NTREE / 2, 512, 0, stream>>>(wid, xzT, xhT, xrT, WzT2, WhT2, UrT2, hsb);
    heads<<<768 + 1520, 256, 0, stream>>>(wid, tvB, embB, hsb, W1T, WoT, UwT,
                                          Wb, Wob, Ubias, Usw, Usb, accb);
    fin_kernel<<<1, 256, 0, stream>>>(accb, (float*)d_out);
}

// Round 18
// 383.533 us; speedup vs baseline: 1.3260x; 1.1698x over previous
//
#include <hip/hip_runtime.h>
#include <math.h>

#define NTREE 512
#define NNODE 48
#define HD 256
#define LD 64
#define VOC 800
#define TSTEP 94
#define NFWD 47

typedef __attribute__((ext_vector_type(8))) short s8v;   // 8 bf16 (4 VGPRs)
typedef __attribute__((ext_vector_type(4))) float f4v;   // 4 fp32 acc

// fast device transcendentals (v_exp_f32 + v_rcp_f32), GRU-only
__device__ __forceinline__ float sigm_f(float x) {
    return __builtin_amdgcn_rcpf(1.f + __expf(-x));
}
__device__ __forceinline__ float tanh_f(float x) {
    return 1.f - 2.f * __builtin_amdgcn_rcpf(1.f + __expf(2.f * x));
}

__device__ __forceinline__ float bfu(unsigned short u) {
    union { unsigned int i; float f; } c; c.i = ((unsigned int)u) << 16; return c.f;
}
__device__ __forceinline__ unsigned short f2bf(float f) {
    union { float f; unsigned int u; } c; c.f = f;
    return (unsigned short)((c.u + 0x7fffu + ((c.u >> 16) & 1u)) >> 16);
}
__device__ __forceinline__ s8v frag(const unsigned short* p) {
    union { int4 i; s8v v; } u; u.i = *(const int4*)p; return u.v;
}
__device__ __forceinline__ s8v zfrag() {
    union { int4 i; s8v v; } u; u.i = make_int4(0, 0, 0, 0); return u.v;
}
// LDS-only barrier: global ops (hsb stores, gathers) stay in flight.
__device__ __forceinline__ void bar_lgkm() {
    asm volatile("s_waitcnt lgkmcnt(0)\n\ts_barrier" ::: "memory");
}

// ---------------------------------------------------------------------------
// Precompute x-projections for all 800 vocab words (biases folded in).
// ---------------------------------------------------------------------------
#define PV 8
__global__ __launch_bounds__(256) void prep_xproj(
    const float* __restrict__ emb,
    const float* __restrict__ Wz, const float* __restrict__ bz,
    const float* __restrict__ Wh, const float* __restrict__ bh,
    const float* __restrict__ Wr, const float* __restrict__ br,
    float* __restrict__ xzT, float* __restrict__ xhT, float* __restrict__ xrT)
{
    __shared__ float embL[PV][HD];
    const int j = threadIdx.x;
    const int v0 = blockIdx.x * PV;
    for (int r = 0; r < PV; ++r) embL[r][j] = emb[(v0 + r) * HD + j];
    __syncthreads();

    float az[PV], ah[PV], ar[PV];
#pragma unroll
    for (int r = 0; r < PV; ++r) { az[r] = bz[j]; ah[r] = bh[j]; ar[r] = br[j]; }
    for (int i = 0; i < HD; i += 4) {
        float wz0 = Wz[(i + 0) * HD + j], wz1 = Wz[(i + 1) * HD + j];
        float wz2 = Wz[(i + 2) * HD + j], wz3 = Wz[(i + 3) * HD + j];
        float wh0 = Wh[(i + 0) * HD + j], wh1 = Wh[(i + 1) * HD + j];
        float wh2 = Wh[(i + 2) * HD + j], wh3 = Wh[(i + 3) * HD + j];
        float wr0 = Wr[(i + 0) * HD + j], wr1 = Wr[(i + 1) * HD + j];
        float wr2 = Wr[(i + 2) * HD + j], wr3 = Wr[(i + 3) * HD + j];
#pragma unroll
        for (int r = 0; r < PV; ++r) {
            float4 e = *(const float4*)&embL[r][i];
            az[r] += e.x * wz0 + e.y * wz1 + e.z * wz2 + e.w * wz3;
            ah[r] += e.x * wh0 + e.y * wh1 + e.z * wh2 + e.w * wh3;
            ar[r] += e.x * wr0 + e.y * wr1 + e.z * wr2 + e.w * wr3;
        }
    }
#pragma unroll
    for (int r = 0; r < PV; ++r) {
        xzT[(v0 + r) * HD + j] = az[r];
        xhT[(v0 + r) * HD + j] = ah[r];
        xrT[(v0 + r) * HD + j] = ar[r];
    }
}

// ---------------------------------------------------------------------------
// Fused misc prep: [0,4) init acc; [4,772) tcvt3; [772,2084) tcvtQ;
// [2084, 3012) cvtE  (928 blocks exact).
// ---------------------------------------------------------------------------
__global__ __launch_bounds__(256) void prep_misc(
    const float* __restrict__ Wz, const float* __restrict__ Wh,
    const float* __restrict__ Ur,
    const float* __restrict__ Ww, const float* __restrict__ Wow,
    const float* __restrict__ Uw,
    const float* __restrict__ emb, const float* __restrict__ tv,
    unsigned short* __restrict__ WzT, unsigned short* __restrict__ WhT,
    unsigned short* __restrict__ UrT,
    unsigned short* __restrict__ W1T, unsigned short* __restrict__ WoT,
    unsigned short* __restrict__ UwT,
    unsigned short* __restrict__ embB, unsigned short* __restrict__ tvB,
    float* __restrict__ acc)
{
    int b = blockIdx.x;
    if (b < 4) {
        acc[b * 256 + threadIdx.x] = 0.f;
    } else if (b < 772) {
        int bb = b - 4;
        const int which = bb >> 8, n = bb & 255, k = threadIdx.x;
        const float* src = (which == 0) ? (Wz + HD * HD) : (which == 1) ? (Wh + HD * HD) : Ur;
        unsigned short* dst = (which == 0) ? WzT : (which == 1) ? WhT : UrT;
        dst[n * HD + k] = f2bf(src[k * HD + n]);
    } else if (b < 2084) {
        int bb = b - 772;
        if (bb < 256) {
            for (int k = threadIdx.x; k < 320; k += 256)
                W1T[bb * 320 + k] = f2bf(Ww[k * 256 + bb]);
        } else if (bb < 1056) {
            int n = bb - 256;
            WoT[n * 256 + threadIdx.x] = f2bf(Wow[threadIdx.x * VOC + n]);
        } else {
            int n = bb - 1056;
            for (int k = threadIdx.x; k < 576; k += 256)
                UwT[n * 576 + k] = f2bf(Uw[k * 256 + n]);
        }
    } else {
        int idx = (b - 2084) * 256 + threadIdx.x;
        if (idx < VOC * HD) embB[idx] = f2bf(emb[idx]);
        else {
            int i2 = idx - VOC * HD;
            if (i2 < NTREE * LD) tvB[i2] = f2bf(tv[i2]);
        }
    }
}

// ---------------------------------------------------------------------------
// GRU v12: forward and backtrack chains are INDEPENDENT recurrences (backtrack
// state restarts at t=47; the h_v coupling is a deferred additive fixup).
// 256 wgs x 512 thr, 2 trees/wg, 4 chains/wg (rows 0-3 of the MFMA A tile:
// [t0 fwd, t1 fwd, t0 bt, t1 bt]), 47 steps. Same per-step shape as gru10:
// Wz/Wh tiles in regs, Ur in LDS, shuffle finalize, 2 lgkm barriers/step.
// A-staging stride 264 keeps the 4-row ds_read_b128 conflict-free.
// hsb rows 47..93 hold raw m_bt; fixup kernel adds hs_fwd afterward.
// ---------------------------------------------------------------------------
#define ASTR 264
__global__ __launch_bounds__(512, 2) void gru12(
    const int* __restrict__ wid,
    const float* __restrict__ xzT, const float* __restrict__ xhT,
    const float* __restrict__ xrT,
    const unsigned short* __restrict__ WzT, const unsigned short* __restrict__ WhT,
    const unsigned short* __restrict__ UrT,
    unsigned short* __restrict__ hsb)
{
    __shared__ unsigned short urL[16 * 8 * 64 * 8];   // 128 KB [tile][kt][lane][8]
    __shared__ unsigned short mBL[2][4][ASTR], armBL[2][4][ASTR];
    __shared__ int widL[2][NNODE];

    const int tid = threadIdx.x;
    const int wave = tid >> 6, lane = tid & 63;
    const int lq = lane >> 4, ln = lane & 15;
    const int b0 = blockIdx.x * 2;
    const int T0 = 2 * wave, T1 = T0 + 1;
    const int ftree = lane >> 5;
    const int fcol  = wave * 32 + (lane & 31);
    const int srcl  = lane & 15;
    const bool hi16 = (lane & 16) != 0;
    const bool hi32 = (lane & 32) != 0;

    if (tid < 2 * NNODE) widL[tid / NNODE][tid % NNODE] =
        wid[(b0 + tid / NNODE) * NNODE + (tid % NNODE)];

#pragma unroll
    for (int s = 0; s < 16; ++s) {
        *(int4*)&urL[((s * 8 + wave) * 64 + lane) * 8] =
            *(const int4*)&UrT[(s * 16 + ln) * HD + wave * 32 + lq * 8];
    }

    s8v wz0[8], wz1[8], wh0[8], wh1[8];
#pragma unroll
    for (int kt = 0; kt < 8; ++kt) {
        const int ko = kt * 32 + lq * 8;
        wz0[kt] = frag(&WzT[(T0 * 16 + ln) * HD + ko]);
        wz1[kt] = frag(&WzT[(T1 * 16 + ln) * HD + ko]);
        wh0[kt] = frag(&WhT[(T0 * 16 + ln) * HD + ko]);
        wh1[kt] = frag(&WhT[(T1 * 16 + ln) * HD + ko]);
    }
    __syncthreads();   // widL + urL visible

    // per-lane state for 2 chains: [0]=forward (row s), [1]=backtrack (row 47+s)
    float cxz[2], cxh[2], cxr[2], me2[2] = {0.f, 0.f};
    float nxz[2] = {0.f, 0.f}, nxh[2] = {0.f, 0.f}, nxr[2] = {0.f, 0.f};
    {   // s=0: fwd src=0,dst=1; bt src=47,dst=46
        cxz[0] = xzT[widL[ftree][0] * HD + fcol];
        cxh[0] = xhT[widL[ftree][0] * HD + fcol];
        cxr[0] = xrT[widL[ftree][1] * HD + fcol];
        cxz[1] = xzT[widL[ftree][47] * HD + fcol];
        cxh[1] = xhT[widL[ftree][47] * HD + fcol];
        cxr[1] = xrT[widL[ftree][46] * HD + fcol];
    }

    for (int s = 0; s < NFWD; ++s) {
        const int par = s & 1, nxt = par ^ 1;
        const bool hp = (s != 0);

        // ---- prefetch for s+1 (registers only) ----
        {
            const int sn = s + 1;
            if (sn < NFWD) {
                const int un = NFWD - sn;
                nxz[0] = xzT[widL[ftree][sn] * HD + fcol];
                nxh[0] = xhT[widL[ftree][sn] * HD + fcol];
                nxr[0] = xrT[widL[ftree][sn + 1] * HD + fcol];
                nxz[1] = xzT[widL[ftree][un] * HD + fcol];
                nxh[1] = xhT[widL[ftree][un] * HD + fcol];
                nxr[1] = xrT[widL[ftree][un - 1] * HD + fcol];
            }
        }

        // ---- phase A MFMA + shuffle redistribute: az, ah for both chains ----
        float az[2] = {0.f, 0.f}, ah[2] = {0.f, 0.f};
        if (hp) {
            f4v cz0 = (f4v){0.f,0.f,0.f,0.f}, cz1 = cz0, ch0 = cz0, ch1 = cz0;
#pragma unroll
            for (int kt = 0; kt < 8; ++kt) {
                const int ko = kt * 32 + lq * 8;
                s8v am = (ln < 4) ? frag(&mBL[par][ln][ko]) : zfrag();
                s8v aa = (ln < 4) ? frag(&armBL[par][ln][ko]) : zfrag();
                cz0 = __builtin_amdgcn_mfma_f32_16x16x32_bf16(am, wz0[kt], cz0, 0, 0, 0);
                cz1 = __builtin_amdgcn_mfma_f32_16x16x32_bf16(am, wz1[kt], cz1, 0, 0, 0);
                ch0 = __builtin_amdgcn_mfma_f32_16x16x32_bf16(aa, wh0[kt], ch0, 0, 0, 0);
                ch1 = __builtin_amdgcn_mfma_f32_16x16x32_bf16(aa, wh1[kt], ch1, 0, 0, 0);
            }
            // C rows 0-3 = chains (regs 0-3 of lq==0 lanes). fwd=reg ftree, bt=reg 2+ftree.
            float f0 = __shfl(cz0[0], srcl), f1 = __shfl(cz0[1], srcl);
            float g0 = __shfl(cz1[0], srcl), g1 = __shfl(cz1[1], srcl);
            az[0] = hi16 ? (hi32 ? g1 : g0) : (hi32 ? f1 : f0);
            float f2 = __shfl(cz0[2], srcl), f3 = __shfl(cz0[3], srcl);
            float g2 = __shfl(cz1[2], srcl), g3 = __shfl(cz1[3], srcl);
            az[1] = hi16 ? (hi32 ? g3 : g2) : (hi32 ? f3 : f2);
            float h0 = __shfl(ch0[0], srcl), h1 = __shfl(ch0[1], srcl);
            float i0 = __shfl(ch1[0], srcl), i1 = __shfl(ch1[1], srcl);
            ah[0] = hi16 ? (hi32 ? i1 : i0) : (hi32 ? h1 : h0);
            float h2 = __shfl(ch0[2], srcl), h3 = __shfl(ch0[3], srcl);
            float i2 = __shfl(ch1[2], srcl), i3 = __shfl(ch1[3], srcl);
            ah[1] = hi16 ? (hi32 ? i3 : i2) : (hi32 ? h3 : h2);
        }

        // ---- finalize A (per-lane, 2 chains) ----
        {
#pragma unroll
            for (int c = 0; c < 2; ++c) {
                float azv = cxz[c], ahv = cxh[c], sold = 0.f;
                if (hp) { azv += az[c]; ahv += ah[c]; sold = me2[c]; }
                float z = sigm_f(azv), mt = tanh_f(ahv);
                float me = sold + z * (mt - sold);
                const int row = (c == 0) ? s : (NFWD + s);
                hsb[((size_t)row * NTREE + b0 + ftree) * HD + fcol] = f2bf(me);
                mBL[nxt][c * 2 + ftree][fcol] = f2bf(me);
                me2[c] = me;
            }
        }
        bar_lgkm();

        // ---- phase B MFMA + shuffle: ar = m_e @ Ur ----
        {
            f4v cr0 = (f4v){0.f,0.f,0.f,0.f}, cr1 = cr0;
#pragma unroll
            for (int kt = 0; kt < 8; ++kt) {
                const int ko = kt * 32 + lq * 8;
                s8v a = (ln < 4) ? frag(&mBL[nxt][ln][ko]) : zfrag();
                s8v b0f = frag(&urL[((T0 * 8 + kt) * 64 + lane) * 8]);
                s8v b1f = frag(&urL[((T1 * 8 + kt) * 64 + lane) * 8]);
                cr0 = __builtin_amdgcn_mfma_f32_16x16x32_bf16(a, b0f, cr0, 0, 0, 0);
                cr1 = __builtin_amdgcn_mfma_f32_16x16x32_bf16(a, b1f, cr1, 0, 0, 0);
            }
            float f0 = __shfl(cr0[0], srcl), f1 = __shfl(cr0[1], srcl);
            float g0 = __shfl(cr1[0], srcl), g1 = __shfl(cr1[1], srcl);
            float ar0 = hi16 ? (hi32 ? g1 : g0) : (hi32 ? f1 : f0);
            float f2 = __shfl(cr0[2], srcl), f3 = __shfl(cr0[3], srcl);
            float g2 = __shfl(cr1[2], srcl), g3 = __shfl(cr1[3], srcl);
            float ar1 = hi16 ? (hi32 ? g3 : g2) : (hi32 ? f3 : f2);
            armBL[nxt][0 * 2 + ftree][fcol] = f2bf(sigm_f(cxr[0] + ar0) * me2[0]);
            armBL[nxt][1 * 2 + ftree][fcol] = f2bf(sigm_f(cxr[1] + ar1) * me2[1]);
#pragma unroll
            for (int c = 0; c < 2; ++c) {
                cxz[c] = nxz[c]; cxh[c] = nxh[c]; cxr[c] = nxr[c];
            }
        }
        bar_lgkm();
    }
}

// ---------------------------------------------------------------------------
// Deferred h_v coupling: hs[47+k] += hs[45-k] for k=0..45 (row 93 untouched).
// 46 rows x 128 chunks; 4 elems/thread.
// ---------------------------------------------------------------------------
__global__ __launch_bounds__(256) void fixup(unsigned short* __restrict__ hsb)
{
    const int k = blockIdx.x >> 7;
    const int chunk = blockIdx.x & 127;
    const size_t off = (size_t)chunk * 1024 + threadIdx.x * 4;
    const size_t tgt = (size_t)(NFWD + k) * NTREE * HD + off;
    const size_t src = (size_t)(NFWD - 2 - k) * NTREE * HD + off;
    ushort4 a = *(ushort4*)&hsb[tgt];
    ushort4 c = *(const ushort4*)&hsb[src];
    a.x = f2bf(bfu(a.x) + bfu(c.x));
    a.y = f2bf(bfu(a.y) + bfu(c.y));
    a.z = f2bf(bfu(a.z) + bfu(c.z));
    a.w = f2bf(bfu(a.w) + bfu(c.w));
    *(ushort4*)&hsb[tgt] = a;
}

// ---------------------------------------------------------------------------
// Fused heads: [0,768) = Q, [768,2288) = P. UNCHANGED from R16 champion.
// ---------------------------------------------------------------------------
#define QG 32
#define PG 32
struct QSmem {
    unsigned short X1L[QG][328];
    unsigned short hidL[QG][264];
    int tgts[QG];
    float wred[4][QG][4];
};
struct PSmem {
    unsigned short XL[PG][584];
    int widL[PG];
    float wredp[4][PG];
};

__global__ __launch_bounds__(256) void heads(
    const int* __restrict__ wid,
    const unsigned short* __restrict__ tvB,
    const unsigned short* __restrict__ embB,
    const unsigned short* __restrict__ hsb,
    const unsigned short* __restrict__ W1T,
    const unsigned short* __restrict__ WoT,
    const unsigned short* __restrict__ UwT,
    const float* __restrict__ Wb, const float* __restrict__ Wob,
    const float* __restrict__ Ub,
    const float* __restrict__ Usw, const float* __restrict__ Usb,
    float* __restrict__ acc)
{
    __shared__ __align__(16) char smem[sizeof(QSmem) > sizeof(PSmem) ? sizeof(QSmem) : sizeof(PSmem)];
    const int tid = threadIdx.x;
    const int wave = tid >> 6, lane = tid & 63;
    const int lq = lane >> 4, ln = lane & 15;

    if (blockIdx.x < 768) {
        // ================= Q head =================
        QSmem& S = *(QSmem*)smem;
        const int trow = blockIdx.x >> 4;
        const int b0 = (blockIdx.x & 15) * QG;

        if (tid < QG) S.tgts[tid] = wid[(b0 + tid) * NNODE + trow];
        if (trow == 0) {
            int4 z = make_int4(0, 0, 0, 0);
            for (int idx = tid; idx < QG * 32; idx += 256) {
                int m = idx >> 5, c = idx & 31;
                *(int4*)&S.X1L[m][c * 8] = z;
            }
        } else {
            const unsigned short* hrow = hsb + (size_t)(trow - 1) * NTREE * HD;
            for (int idx = tid; idx < QG * 32; idx += 256) {
                int m = idx >> 5, c = idx & 31;
                *(int4*)&S.X1L[m][c * 8] = *(const int4*)&hrow[(b0 + m) * HD + c * 8];
            }
        }
        for (int idx = tid; idx < QG * 8; idx += 256) {
            int m = idx >> 3, c = idx & 7;
            *(int4*)&S.X1L[m][256 + c * 8] = *(const int4*)&tvB[(b0 + m) * LD + c * 8];
        }
        __syncthreads();

        f4v acc1[2][4];
#pragma unroll
        for (int mt = 0; mt < 2; ++mt)
#pragma unroll
            for (int nt = 0; nt < 4; ++nt) acc1[mt][nt] = (f4v){0.f, 0.f, 0.f, 0.f};
#pragma unroll
        for (int kt = 0; kt < 10; ++kt) {
            s8v a0 = frag(&S.X1L[ln][kt * 32 + lq * 8]);
            s8v a1 = frag(&S.X1L[16 + ln][kt * 32 + lq * 8]);
#pragma unroll
            for (int nt = 0; nt < 4; ++nt) {
                int n = wave * 64 + nt * 16 + ln;
                s8v b = frag(&W1T[n * 320 + kt * 32 + lq * 8]);
                acc1[0][nt] = __builtin_amdgcn_mfma_f32_16x16x32_bf16(a0, b, acc1[0][nt], 0, 0, 0);
                acc1[1][nt] = __builtin_amdgcn_mfma_f32_16x16x32_bf16(a1, b, acc1[1][nt], 0, 0, 0);
            }
        }
#pragma unroll
        for (int nt = 0; nt < 4; ++nt) {
            int col = wave * 64 + nt * 16 + ln;
            float wb = Wb[col];
#pragma unroll
            for (int mt = 0; mt < 2; ++mt)
#pragma unroll
                for (int r = 0; r < 4; ++r)
                    S.hidL[mt * 16 + lq * 4 + r][col] = f2bf(fmaxf(acc1[mt][nt][r] + wb, 0.f));
        }
        __syncthreads();

        // stage 2: hid A-frags cached in registers
        s8v ha0[8], ha1[8];
#pragma unroll
        for (int kt = 0; kt < 8; ++kt) {
            ha0[kt] = frag(&S.hidL[ln][kt * 32 + lq * 8]);
            ha1[kt] = frag(&S.hidL[16 + ln][kt * 32 + lq * 8]);
        }

        int rt[2][4];
#pragma unroll
        for (int mt = 0; mt < 2; ++mt)
#pragma unroll
            for (int r = 0; r < 4; ++r) rt[mt][r] = S.tgts[mt * 16 + lq * 4 + r];
        float mx[2][4], ls[2][4], tg[2][4]; int am[2][4];
#pragma unroll
        for (int mt = 0; mt < 2; ++mt)
#pragma unroll
            for (int r = 0; r < 4; ++r) { mx[mt][r] = -1e30f; ls[mt][r] = 0.f; tg[mt][r] = 0.f; am[mt][r] = 1 << 30; }

        for (int nt = wave; nt < 50; nt += 4) {
            int n = nt * 16 + ln;
            const unsigned short* wrow = WoT + n * 256;
            f4v a2[2];
            a2[0] = (f4v){0.f, 0.f, 0.f, 0.f}; a2[1] = (f4v){0.f, 0.f, 0.f, 0.f};
#pragma unroll
            for (int kt = 0; kt < 8; ++kt) {
                s8v b = frag(&wrow[kt * 32 + lq * 8]);
                a2[0] = __builtin_amdgcn_mfma_f32_16x16x32_bf16(ha0[kt], b, a2[0], 0, 0, 0);
                a2[1] = __builtin_amdgcn_mfma_f32_16x16x32_bf16(ha1[kt], b, a2[1], 0, 0, 0);
            }
            float bias = Wob[n];
#pragma unroll
            for (int mt = 0; mt < 2; ++mt)
#pragma unroll
                for (int r = 0; r < 4; ++r) {
                    float v = a2[mt][r] + bias;
                    if (n == rt[mt][r]) tg[mt][r] = v;
                    float d = v - mx[mt][r];
                    float e = __expf(-fabsf(d));
                    bool newmax = d > 0.f;
                    ls[mt][r] = fmaf(ls[mt][r], newmax ? e : 1.f, newmax ? 1.f : e);
                    if (newmax) { mx[mt][r] = v; am[mt][r] = n; }
                }
        }

#pragma unroll
        for (int s = 1; s < 16; s <<= 1) {
#pragma unroll
            for (int mt = 0; mt < 2; ++mt)
#pragma unroll
                for (int r = 0; r < 4; ++r) {
                    float mo = __shfl_xor(mx[mt][r], s);
                    float lo = __shfl_xor(ls[mt][r], s);
                    int   ao = __shfl_xor(am[mt][r], s);
                    float to = __shfl_xor(tg[mt][r], s);
                    tg[mt][r] += to;
                    float nm = fmaxf(mx[mt][r], mo);
                    ls[mt][r] = ls[mt][r] * __expf(mx[mt][r] - nm) + lo * __expf(mo - nm);
                    if (mo > mx[mt][r] || (mo == mx[mt][r] && ao < am[mt][r])) am[mt][r] = ao;
                    mx[mt][r] = nm;
                }
        }
        if (ln == 0) {
#pragma unroll
            for (int mt = 0; mt < 2; ++mt)
#pragma unroll
                for (int r = 0; r < 4; ++r) {
                    int row = mt * 16 + lq * 4 + r;
                    S.wred[wave][row][0] = mx[mt][r];
                    S.wred[wave][row][1] = ls[mt][r];
                    S.wred[wave][row][2] = __int_as_float(am[mt][r]);
                    S.wred[wave][row][3] = tg[mt][r];
                }
        }
        __syncthreads();

        float lossv = 0.f, corrv = 0.f;
        if (tid < QG) {
            float m_ = -1e30f, l_ = 0.f, t_ = 0.f; int a_ = 1 << 30;
#pragma unroll
            for (int w = 0; w < 4; ++w) {
                float mo = S.wred[w][tid][0], lo = S.wred[w][tid][1], to = S.wred[w][tid][3];
                int ao = __float_as_int(S.wred[w][tid][2]);
                t_ += to;
                float nm = fmaxf(m_, mo);
                l_ = l_ * __expf(m_ - nm) + lo * __expf(mo - nm);
                if (mo > m_ || (mo == m_ && ao < a_)) a_ = ao;
                m_ = nm;
            }
            lossv = m_ + logf(l_) - t_;
            corrv = (a_ == S.tgts[tid]) ? 1.f : 0.f;
        }
        if (wave == 0) {
            for (int s = 32; s; s >>= 1) {
                lossv += __shfl_down(lossv, s);
                corrv += __shfl_down(corrv, s);
            }
            if (tid == 0) {
                int slot = blockIdx.x & 255;
                atomicAdd(&acc[0 * 256 + slot], lossv);
                atomicAdd(&acc[2 * 256 + slot], corrv);
            }
        }
    } else {
        // ================= P head =================
        PSmem& S = *(PSmem*)smem;
        const int pb = blockIdx.x - 768;
        const int trow = pb >> 4;
        const int b0 = (pb & 15) * PG;
        const int node = (trow == 0) ? 0 : ((trow <= NFWD) ? trow : (TSTEP - trow));

        if (tid < PG) S.widL[tid] = wid[(b0 + tid) * NNODE + node];
        __syncthreads();

        for (int idx = tid; idx < PG * 32; idx += 256) {
            int m = idx >> 5, c = idx & 31;
            *(int4*)&S.XL[m][c * 8] = *(const int4*)&embB[S.widL[m] * HD + c * 8];
        }
        if (trow == 0) {
            int4 z = make_int4(0, 0, 0, 0);
            for (int idx = tid; idx < PG * 32; idx += 256) {
                int m = idx >> 5, c = idx & 31;
                *(int4*)&S.XL[m][256 + c * 8] = z;
            }
        } else {
            const unsigned short* hrow = hsb + (size_t)(trow - 1) * NTREE * HD;
            for (int idx = tid; idx < PG * 32; idx += 256) {
                int m = idx >> 5, c = idx & 31;
                *(int4*)&S.XL[m][256 + c * 8] = *(const int4*)&hrow[(b0 + m) * HD + c * 8];
            }
        }
        for (int idx = tid; idx < PG * 8; idx += 256) {
            int m = idx >> 3, c = idx & 7;
            *(int4*)&S.XL[m][512 + c * 8] = *(const int4*)&tvB[(b0 + m) * LD + c * 8];
        }
        __syncthreads();

        f4v a1[2][4];
#pragma unroll
        for (int mt = 0; mt < 2; ++mt)
#pragma unroll
            for (int nt = 0; nt < 4; ++nt) a1[mt][nt] = (f4v){0.f, 0.f, 0.f, 0.f};
        for (int kt = 0; kt < 18; ++kt) {
            s8v a0 = frag(&S.XL[ln][kt * 32 + lq * 8]);
            s8v am_ = frag(&S.XL[16 + ln][kt * 32 + lq * 8]);
#pragma unroll
            for (int nt = 0; nt < 4; ++nt) {
                int n = wave * 64 + nt * 16 + ln;
                s8v b = frag(&UwT[n * 576 + kt * 32 + lq * 8]);
                a1[0][nt] = __builtin_amdgcn_mfma_f32_16x16x32_bf16(a0, b, a1[0][nt], 0, 0, 0);
                a1[1][nt] = __builtin_amdgcn_mfma_f32_16x16x32_bf16(am_, b, a1[1][nt], 0, 0, 0);
            }
        }
        float part[2][4] = {{0, 0, 0, 0}, {0, 0, 0, 0}};
#pragma unroll
        for (int nt = 0; nt < 4; ++nt) {
            int n = wave * 64 + nt * 16 + ln;
            float ub = Ub[n], us = Usw[n];
#pragma unroll
            for (int mt = 0; mt < 2; ++mt)
#pragma unroll
                for (int r = 0; r < 4; ++r)
                    part[mt][r] += fmaxf(a1[mt][nt][r] + ub, 0.f) * us;
        }
#pragma unroll
        for (int s = 1; s < 16; s <<= 1) {
#pragma unroll
            for (int mt = 0; mt < 2; ++mt)
#pragma unroll
                for (int r = 0; r < 4; ++r)
                    part[mt][r] += __shfl_xor(part[mt][r], s);
        }
        if (ln == 0) {
#pragma unroll
            for (int mt = 0; mt < 2; ++mt)
#pragma unroll
                for (int r = 0; r < 4; ++r)
                    S.wredp[wave][mt * 16 + lq * 4 + r] = part[mt][r];
        }
        __syncthreads();

        float lossv = 0.f, corrv = 0.f;
        if (tid < PG) {
            float p = S.wredp[0][tid] + S.wredp[1][tid] + S.wredp[2][tid] + S.wredp[3][tid] + Usb[0];
            float tgt = (trow < NFWD) ? 1.f : 0.f;
            lossv = fmaxf(p, 0.f) - p * tgt + log1pf(expf(-fabsf(p)));
            corrv = (((p > 0.f) ? 1 : 0) == ((trow < NFWD) ? 1 : 0)) ? 1.f : 0.f;
        }
        if (wave == 0) {
            for (int s = 32; s; s >>= 1) {
                lossv += __shfl_down(lossv, s);
                corrv += __shfl_down(corrv, s);
            }
            if (tid == 0) {
                int slot = blockIdx.x & 255;
                atomicAdd(&acc[1 * 256 + slot], lossv);
                atomicAdd(&acc[3 * 256 + slot], corrv);
            }
        }
    }
}

__global__ void fin_kernel(const float* __restrict__ acc, float* __restrict__ out) {
    const int tid = threadIdx.x;
    const int c = tid >> 6, lane = tid & 63;
    float v = 0.f;
    for (int i = lane; i < 256; i += 64) v += acc[c * 256 + i];
    for (int s = 32; s; s >>= 1) v += __shfl_down(v, s);
    if (lane == 0) {
        const float sc[4] = {1.f / 512.f, 1.f / 512.f, 1.f / 24576.f, 1.f / 48640.f};
        out[c] = v * sc[c];
    }
}

extern "C" void kernel_launch(void* const* d_in, const int* in_sizes, int n_in,
                              void* d_out, int out_size, void* d_ws, size_t ws_size,
                              hipStream_t stream) {
    const int*   wid  = (const int*)  d_in[12];
    const float* tv   = (const float*)d_in[13];
    const float* emb  = (const float*)d_in[14];
    const float* Wz   = (const float*)d_in[15];
    const float* bz   = (const float*)d_in[16];
    const float* Wr   = (const float*)d_in[17];
    const float* Ur   = (const float*)d_in[18];
    const float* br   = (const float*)d_in[19];
    const float* Wh   = (const float*)d_in[20];
    const float* bh   = (const float*)d_in[21];
    const float* Ww   = (const float*)d_in[22];
    const float* Wb   = (const float*)d_in[23];
    const float* Uw   = (const float*)d_in[24];
    const float* Ubias= (const float*)d_in[25];
    const float* Wow  = (const float*)d_in[26];
    const float* Wob  = (const float*)d_in[27];
    const float* Usw  = (const float*)d_in[28];
    const float* Usb  = (const float*)d_in[29];

    char* w = (char*)d_ws;
    float* accb = (float*)w;                                 // 4 KB
    float* xzT  = (float*)(w + 4096);                        // 800*256 f32
    float* xhT  = (float*)(w + 823296);
    float* xrT  = (float*)(w + 1642496);
    unsigned short* WzT2 = (unsigned short*)(w + 2461696);   // [256 n][256 k] bf16
    unsigned short* WhT2 = (unsigned short*)(w + 2592768);
    unsigned short* UrT2 = (unsigned short*)(w + 2723840);
    unsigned short* hsb  = (unsigned short*)(w + 2854912);   // 94*512*256 bf16
    unsigned short* W1T  = (unsigned short*)(w + 27496448);  // [256][320]
    unsigned short* WoT  = (unsigned short*)(w + 27660288);  // [800][256]
    unsigned short* UwT  = (unsigned short*)(w + 28069888);  // [256][576]
    unsigned short* embB = (unsigned short*)(w + 28364800);  // [800][256]
    unsigned short* tvB  = (unsigned short*)(w + 28774400);  // [512][64]

    prep_xproj<<<VOC / PV, 256, 0, stream>>>(emb, Wz, bz, Wh, bh, Wr, br, xzT, xhT, xrT);
    prep_misc<<<3012, 256, 0, stream>>>(Wz, Wh, Ur, Ww, Wow, Uw, emb, tv,
                                        WzT2, WhT2, UrT2, W1T, WoT, UwT,
                                        embB, tvB, accb);
    gru12<<<NTREE / 2, 512, 0, stream>>>(wid, xzT, xhT, xrT, WzT2, WhT2, UrT2, hsb);
    fixup<<<46 * 128, 256, 0, stream>>>(hsb);
    heads<<<768 + 1520, 256, 0, stream>>>(wid, tvB, embB, hsb, W1T, WoT, UwT,
                                          Wb, Wob, Ubias, Usw, Usb, accb);
    fin_kernel<<<1, 256, 0, stream>>>(accb, (float*)d_out);
}

// Round 19
// 382.980 us; speedup vs baseline: 1.3280x; 1.0014x over previous
//
#include <hip/hip_runtime.h>
#include <math.h>

#define NTREE 512
#define NNODE 48
#define HD 256
#define LD 64
#define VOC 800
#define TSTEP 94
#define NFWD 47

typedef __attribute__((ext_vector_type(8))) short s8v;   // 8 bf16 (4 VGPRs)
typedef __attribute__((ext_vector_type(4))) float f4v;   // 4 fp32 acc

// fast device transcendentals (v_exp_f32 + v_rcp_f32), GRU-only
__device__ __forceinline__ float sigm_f(float x) {
    return __builtin_amdgcn_rcpf(1.f + __expf(-x));
}
__device__ __forceinline__ float tanh_f(float x) {
    return 1.f - 2.f * __builtin_amdgcn_rcpf(1.f + __expf(2.f * x));
}

__device__ __forceinline__ float bfu(unsigned short u) {
    union { unsigned int i; float f; } c; c.i = ((unsigned int)u) << 16; return c.f;
}
__device__ __forceinline__ unsigned short f2bf(float f) {
    union { float f; unsigned int u; } c; c.f = f;
    return (unsigned short)((c.u + 0x7fffu + ((c.u >> 16) & 1u)) >> 16);
}
__device__ __forceinline__ s8v frag(const unsigned short* p) {
    union { int4 i; s8v v; } u; u.i = *(const int4*)p; return u.v;
}
__device__ __forceinline__ s8v zfrag() {
    union { int4 i; s8v v; } u; u.i = make_int4(0, 0, 0, 0); return u.v;
}
// LDS-only barrier: global ops (hsb stores, gathers) stay in flight.
__device__ __forceinline__ void bar_lgkm() {
    asm volatile("s_waitcnt lgkmcnt(0)\n\ts_barrier" ::: "memory");
}

// ---------------------------------------------------------------------------
// Precompute x-projections for all 800 vocab words (biases folded in).
// ---------------------------------------------------------------------------
#define PV 8
__global__ __launch_bounds__(256) void prep_xproj(
    const float* __restrict__ emb,
    const float* __restrict__ Wz, const float* __restrict__ bz,
    const float* __restrict__ Wh, const float* __restrict__ bh,
    const float* __restrict__ Wr, const float* __restrict__ br,
    float* __restrict__ xzT, float* __restrict__ xhT, float* __restrict__ xrT)
{
    __shared__ float embL[PV][HD];
    const int j = threadIdx.x;
    const int v0 = blockIdx.x * PV;
    for (int r = 0; r < PV; ++r) embL[r][j] = emb[(v0 + r) * HD + j];
    __syncthreads();

    float az[PV], ah[PV], ar[PV];
#pragma unroll
    for (int r = 0; r < PV; ++r) { az[r] = bz[j]; ah[r] = bh[j]; ar[r] = br[j]; }
    for (int i = 0; i < HD; i += 4) {
        float wz0 = Wz[(i + 0) * HD + j], wz1 = Wz[(i + 1) * HD + j];
        float wz2 = Wz[(i + 2) * HD + j], wz3 = Wz[(i + 3) * HD + j];
        float wh0 = Wh[(i + 0) * HD + j], wh1 = Wh[(i + 1) * HD + j];
        float wh2 = Wh[(i + 2) * HD + j], wh3 = Wh[(i + 3) * HD + j];
        float wr0 = Wr[(i + 0) * HD + j], wr1 = Wr[(i + 1) * HD + j];
        float wr2 = Wr[(i + 2) * HD + j], wr3 = Wr[(i + 3) * HD + j];
#pragma unroll
        for (int r = 0; r < PV; ++r) {
            float4 e = *(const float4*)&embL[r][i];
            az[r] += e.x * wz0 + e.y * wz1 + e.z * wz2 + e.w * wz3;
            ah[r] += e.x * wh0 + e.y * wh1 + e.z * wh2 + e.w * wh3;
            ar[r] += e.x * wr0 + e.y * wr1 + e.z * wr2 + e.w * wr3;
        }
    }
#pragma unroll
    for (int r = 0; r < PV; ++r) {
        xzT[(v0 + r) * HD + j] = az[r];
        xhT[(v0 + r) * HD + j] = ah[r];
        xrT[(v0 + r) * HD + j] = ar[r];
    }
}

// ---------------------------------------------------------------------------
// Fused misc prep: [0,4) init acc; [4,772) tcvt3; [772,2084) tcvtQ;
// [2084, 3012) cvtE  (928 blocks exact).
// ---------------------------------------------------------------------------
__global__ __launch_bounds__(256) void prep_misc(
    const float* __restrict__ Wz, const float* __restrict__ Wh,
    const float* __restrict__ Ur,
    const float* __restrict__ Ww, const float* __restrict__ Wow,
    const float* __restrict__ Uw,
    const float* __restrict__ emb, const float* __restrict__ tv,
    unsigned short* __restrict__ WzT, unsigned short* __restrict__ WhT,
    unsigned short* __restrict__ UrT,
    unsigned short* __restrict__ W1T, unsigned short* __restrict__ WoT,
    unsigned short* __restrict__ UwT,
    unsigned short* __restrict__ embB, unsigned short* __restrict__ tvB,
    float* __restrict__ acc)
{
    int b = blockIdx.x;
    if (b < 4) {
        acc[b * 256 + threadIdx.x] = 0.f;
    } else if (b < 772) {
        int bb = b - 4;
        const int which = bb >> 8, n = bb & 255, k = threadIdx.x;
        const float* src = (which == 0) ? (Wz + HD * HD) : (which == 1) ? (Wh + HD * HD) : Ur;
        unsigned short* dst = (which == 0) ? WzT : (which == 1) ? WhT : UrT;
        dst[n * HD + k] = f2bf(src[k * HD + n]);
    } else if (b < 2084) {
        int bb = b - 772;
        if (bb < 256) {
            for (int k = threadIdx.x; k < 320; k += 256)
                W1T[bb * 320 + k] = f2bf(Ww[k * 256 + bb]);
        } else if (bb < 1056) {
            int n = bb - 256;
            WoT[n * 256 + threadIdx.x] = f2bf(Wow[threadIdx.x * VOC + n]);
        } else {
            int n = bb - 1056;
            for (int k = threadIdx.x; k < 576; k += 256)
                UwT[n * 576 + k] = f2bf(Uw[k * 256 + n]);
        }
    } else {
        int idx = (b - 2084) * 256 + threadIdx.x;
        if (idx < VOC * HD) embB[idx] = f2bf(emb[idx]);
        else {
            int i2 = idx - VOC * HD;
            if (i2 < NTREE * LD) tvB[i2] = f2bf(tv[i2]);
        }
    }
}

// ---------------------------------------------------------------------------
// GRU v12 (champion): fwd+backtrack chains in parallel, 47 steps, deferred
// additive fixup. UNCHANGED from R18.
// ---------------------------------------------------------------------------
#define ASTR 264
__global__ __launch_bounds__(512, 2) void gru12(
    const int* __restrict__ wid,
    const float* __restrict__ xzT, const float* __restrict__ xhT,
    const float* __restrict__ xrT,
    const unsigned short* __restrict__ WzT, const unsigned short* __restrict__ WhT,
    const unsigned short* __restrict__ UrT,
    unsigned short* __restrict__ hsb)
{
    __shared__ unsigned short urL[16 * 8 * 64 * 8];   // 128 KB [tile][kt][lane][8]
    __shared__ unsigned short mBL[2][4][ASTR], armBL[2][4][ASTR];
    __shared__ int widL[2][NNODE];

    const int tid = threadIdx.x;
    const int wave = tid >> 6, lane = tid & 63;
    const int lq = lane >> 4, ln = lane & 15;
    const int b0 = blockIdx.x * 2;
    const int T0 = 2 * wave, T1 = T0 + 1;
    const int ftree = lane >> 5;
    const int fcol  = wave * 32 + (lane & 31);
    const int srcl  = lane & 15;
    const bool hi16 = (lane & 16) != 0;
    const bool hi32 = (lane & 32) != 0;

    if (tid < 2 * NNODE) widL[tid / NNODE][tid % NNODE] =
        wid[(b0 + tid / NNODE) * NNODE + (tid % NNODE)];

#pragma unroll
    for (int s = 0; s < 16; ++s) {
        *(int4*)&urL[((s * 8 + wave) * 64 + lane) * 8] =
            *(const int4*)&UrT[(s * 16 + ln) * HD + wave * 32 + lq * 8];
    }

    s8v wz0[8], wz1[8], wh0[8], wh1[8];
#pragma unroll
    for (int kt = 0; kt < 8; ++kt) {
        const int ko = kt * 32 + lq * 8;
        wz0[kt] = frag(&WzT[(T0 * 16 + ln) * HD + ko]);
        wz1[kt] = frag(&WzT[(T1 * 16 + ln) * HD + ko]);
        wh0[kt] = frag(&WhT[(T0 * 16 + ln) * HD + ko]);
        wh1[kt] = frag(&WhT[(T1 * 16 + ln) * HD + ko]);
    }
    __syncthreads();   // widL + urL visible

    // per-lane state for 2 chains: [0]=forward (row s), [1]=backtrack (row 47+s)
    float cxz[2], cxh[2], cxr[2], me2[2] = {0.f, 0.f};
    float nxz[2] = {0.f, 0.f}, nxh[2] = {0.f, 0.f}, nxr[2] = {0.f, 0.f};
    {   // s=0: fwd src=0,dst=1; bt src=47,dst=46
        cxz[0] = xzT[widL[ftree][0] * HD + fcol];
        cxh[0] = xhT[widL[ftree][0] * HD + fcol];
        cxr[0] = xrT[widL[ftree][1] * HD + fcol];
        cxz[1] = xzT[widL[ftree][47] * HD + fcol];
        cxh[1] = xhT[widL[ftree][47] * HD + fcol];
        cxr[1] = xrT[widL[ftree][46] * HD + fcol];
    }

    for (int s = 0; s < NFWD; ++s) {
        const int par = s & 1, nxt = par ^ 1;
        const bool hp = (s != 0);

        // ---- prefetch for s+1 (registers only) ----
        {
            const int sn = s + 1;
            if (sn < NFWD) {
                const int un = NFWD - sn;
                nxz[0] = xzT[widL[ftree][sn] * HD + fcol];
                nxh[0] = xhT[widL[ftree][sn] * HD + fcol];
                nxr[0] = xrT[widL[ftree][sn + 1] * HD + fcol];
                nxz[1] = xzT[widL[ftree][un] * HD + fcol];
                nxh[1] = xhT[widL[ftree][un] * HD + fcol];
                nxr[1] = xrT[widL[ftree][un - 1] * HD + fcol];
            }
        }

        // ---- phase A MFMA + shuffle redistribute: az, ah for both chains ----
        float az[2] = {0.f, 0.f}, ah[2] = {0.f, 0.f};
        if (hp) {
            f4v cz0 = (f4v){0.f,0.f,0.f,0.f}, cz1 = cz0, ch0 = cz0, ch1 = cz0;
#pragma unroll
            for (int kt = 0; kt < 8; ++kt) {
                const int ko = kt * 32 + lq * 8;
                s8v am = (ln < 4) ? frag(&mBL[par][ln][ko]) : zfrag();
                s8v aa = (ln < 4) ? frag(&armBL[par][ln][ko]) : zfrag();
                cz0 = __builtin_amdgcn_mfma_f32_16x16x32_bf16(am, wz0[kt], cz0, 0, 0, 0);
                cz1 = __builtin_amdgcn_mfma_f32_16x16x32_bf16(am, wz1[kt], cz1, 0, 0, 0);
                ch0 = __builtin_amdgcn_mfma_f32_16x16x32_bf16(aa, wh0[kt], ch0, 0, 0, 0);
                ch1 = __builtin_amdgcn_mfma_f32_16x16x32_bf16(aa, wh1[kt], ch1, 0, 0, 0);
            }
            // C rows 0-3 = chains (regs 0-3 of lq==0 lanes). fwd=reg ftree, bt=reg 2+ftree.
            float f0 = __shfl(cz0[0], srcl), f1 = __shfl(cz0[1], srcl);
            float g0 = __shfl(cz1[0], srcl), g1 = __shfl(cz1[1], srcl);
            az[0] = hi16 ? (hi32 ? g1 : g0) : (hi32 ? f1 : f0);
            float f2 = __shfl(cz0[2], srcl), f3 = __shfl(cz0[3], srcl);
            float g2 = __shfl(cz1[2], srcl), g3 = __shfl(cz1[3], srcl);
            az[1] = hi16 ? (hi32 ? g3 : g2) : (hi32 ? f3 : f2);
            float h0 = __shfl(ch0[0], srcl), h1 = __shfl(ch0[1], srcl);
            float i0 = __shfl(ch1[0], srcl), i1 = __shfl(ch1[1], srcl);
            ah[0] = hi16 ? (hi32 ? i1 : i0) : (hi32 ? h1 : h0);
            float h2 = __shfl(ch0[2], srcl), h3 = __shfl(ch0[3], srcl);
            float i2 = __shfl(ch1[2], srcl), i3 = __shfl(ch1[3], srcl);
            ah[1] = hi16 ? (hi32 ? i3 : i2) : (hi32 ? h3 : h2);
        }

        // ---- finalize A (per-lane, 2 chains) ----
        {
#pragma unroll
            for (int c = 0; c < 2; ++c) {
                float azv = cxz[c], ahv = cxh[c], sold = 0.f;
                if (hp) { azv += az[c]; ahv += ah[c]; sold = me2[c]; }
                float z = sigm_f(azv), mt = tanh_f(ahv);
                float me = sold + z * (mt - sold);
                const int row = (c == 0) ? s : (NFWD + s);
                hsb[((size_t)row * NTREE + b0 + ftree) * HD + fcol] = f2bf(me);
                mBL[nxt][c * 2 + ftree][fcol] = f2bf(me);
                me2[c] = me;
            }
        }
        bar_lgkm();

        // ---- phase B MFMA + shuffle: ar = m_e @ Ur ----
        {
            f4v cr0 = (f4v){0.f,0.f,0.f,0.f}, cr1 = cr0;
#pragma unroll
            for (int kt = 0; kt < 8; ++kt) {
                const int ko = kt * 32 + lq * 8;
                s8v a = (ln < 4) ? frag(&mBL[nxt][ln][ko]) : zfrag();
                s8v b0f = frag(&urL[((T0 * 8 + kt) * 64 + lane) * 8]);
                s8v b1f = frag(&urL[((T1 * 8 + kt) * 64 + lane) * 8]);
                cr0 = __builtin_amdgcn_mfma_f32_16x16x32_bf16(a, b0f, cr0, 0, 0, 0);
                cr1 = __builtin_amdgcn_mfma_f32_16x16x32_bf16(a, b1f, cr1, 0, 0, 0);
            }
            float f0 = __shfl(cr0[0], srcl), f1 = __shfl(cr0[1], srcl);
            float g0 = __shfl(cr1[0], srcl), g1 = __shfl(cr1[1], srcl);
            float ar0 = hi16 ? (hi32 ? g1 : g0) : (hi32 ? f1 : f0);
            float f2 = __shfl(cr0[2], srcl), f3 = __shfl(cr0[3], srcl);
            float g2 = __shfl(cr1[2], srcl), g3 = __shfl(cr1[3], srcl);
            float ar1 = hi16 ? (hi32 ? g3 : g2) : (hi32 ? f3 : f2);
            armBL[nxt][0 * 2 + ftree][fcol] = f2bf(sigm_f(cxr[0] + ar0) * me2[0]);
            armBL[nxt][1 * 2 + ftree][fcol] = f2bf(sigm_f(cxr[1] + ar1) * me2[1]);
#pragma unroll
            for (int c = 0; c < 2; ++c) {
                cxz[c] = nxz[c]; cxh[c] = nxh[c]; cxr[c] = nxr[c];
            }
        }
        bar_lgkm();
    }
}

// ---------------------------------------------------------------------------
// Deferred h_v coupling: hs[47+k] += hs[45-k] for k=0..45 (row 93 untouched).
// ---------------------------------------------------------------------------
__global__ __launch_bounds__(256) void fixup(unsigned short* __restrict__ hsb)
{
    const int k = blockIdx.x >> 7;
    const int chunk = blockIdx.x & 127;
    const size_t off = (size_t)chunk * 1024 + threadIdx.x * 4;
    const size_t tgt = (size_t)(NFWD + k) * NTREE * HD + off;
    const size_t src = (size_t)(NFWD - 2 - k) * NTREE * HD + off;
    ushort4 a = *(ushort4*)&hsb[tgt];
    ushort4 c = *(const ushort4*)&hsb[src];
    a.x = f2bf(bfu(a.x) + bfu(c.x));
    a.y = f2bf(bfu(a.y) + bfu(c.y));
    a.z = f2bf(bfu(a.z) + bfu(c.z));
    a.w = f2bf(bfu(a.w) + bfu(c.w));
    *(ushort4*)&hsb[tgt] = a;
}

// ---------------------------------------------------------------------------
// Fused heads v3: chunked K-staging through ONE [32][264] buffer per block
// (lifetimes: Q: h -> tv -> hidL-transpose; P: emb -> h -> tv). LDS/block
// drops 40K -> ~19K => 8 blocks/CU (was 3) for latency hiding. Identical
// MFMA order/arithmetic to R18.
// ---------------------------------------------------------------------------
#define QG 32
#define PG 32
#define XSTR 264
struct QSmem {
    unsigned short XB[QG][XSTR];
    int tgts[QG];
    float wred[4][QG][4];
};
struct PSmem {
    unsigned short XB[PG][XSTR];
    int widL[PG];
    float wredp[4][PG];
};

__global__ __launch_bounds__(256) void heads(
    const int* __restrict__ wid,
    const unsigned short* __restrict__ tvB,
    const unsigned short* __restrict__ embB,
    const unsigned short* __restrict__ hsb,
    const unsigned short* __restrict__ W1T,
    const unsigned short* __restrict__ WoT,
    const unsigned short* __restrict__ UwT,
    const float* __restrict__ Wb, const float* __restrict__ Wob,
    const float* __restrict__ Ub,
    const float* __restrict__ Usw, const float* __restrict__ Usb,
    float* __restrict__ acc)
{
    __shared__ __align__(16) char smem[sizeof(QSmem) > sizeof(PSmem) ? sizeof(QSmem) : sizeof(PSmem)];
    const int tid = threadIdx.x;
    const int wave = tid >> 6, lane = tid & 63;
    const int lq = lane >> 4, ln = lane & 15;

    if (blockIdx.x < 768) {
        // ================= Q head =================
        QSmem& S = *(QSmem*)smem;
        const int trow = blockIdx.x >> 4;
        const int b0 = (blockIdx.x & 15) * QG;

        if (tid < QG) S.tgts[tid] = wid[(b0 + tid) * NNODE + trow];

        // ---- chunk 0: h rows (kt 0..7) ----
        if (trow == 0) {
            int4 z = make_int4(0, 0, 0, 0);
            for (int idx = tid; idx < QG * 32; idx += 256) {
                int m = idx >> 5, c = idx & 31;
                *(int4*)&S.XB[m][c * 8] = z;
            }
        } else {
            const unsigned short* hrow = hsb + (size_t)(trow - 1) * NTREE * HD;
            for (int idx = tid; idx < QG * 32; idx += 256) {
                int m = idx >> 5, c = idx & 31;
                *(int4*)&S.XB[m][c * 8] = *(const int4*)&hrow[(b0 + m) * HD + c * 8];
            }
        }
        __syncthreads();

        f4v acc1[2][4];
#pragma unroll
        for (int mt = 0; mt < 2; ++mt)
#pragma unroll
            for (int nt = 0; nt < 4; ++nt) acc1[mt][nt] = (f4v){0.f, 0.f, 0.f, 0.f};
#pragma unroll
        for (int kt = 0; kt < 8; ++kt) {
            s8v a0 = frag(&S.XB[ln][kt * 32 + lq * 8]);
            s8v a1 = frag(&S.XB[16 + ln][kt * 32 + lq * 8]);
#pragma unroll
            for (int nt = 0; nt < 4; ++nt) {
                int n = wave * 64 + nt * 16 + ln;
                s8v b = frag(&W1T[n * 320 + kt * 32 + lq * 8]);
                acc1[0][nt] = __builtin_amdgcn_mfma_f32_16x16x32_bf16(a0, b, acc1[0][nt], 0, 0, 0);
                acc1[1][nt] = __builtin_amdgcn_mfma_f32_16x16x32_bf16(a1, b, acc1[1][nt], 0, 0, 0);
            }
        }
        __syncthreads();

        // ---- chunk 1: tv (kt 8..9) ----
        if (tid < QG * 8) {
            int m = tid >> 3, c = tid & 7;
            *(int4*)&S.XB[m][c * 8] = *(const int4*)&tvB[(b0 + m) * LD + c * 8];
        }
        __syncthreads();
#pragma unroll
        for (int kt = 8; kt < 10; ++kt) {
            s8v a0 = frag(&S.XB[ln][(kt - 8) * 32 + lq * 8]);
            s8v a1 = frag(&S.XB[16 + ln][(kt - 8) * 32 + lq * 8]);
#pragma unroll
            for (int nt = 0; nt < 4; ++nt) {
                int n = wave * 64 + nt * 16 + ln;
                s8v b = frag(&W1T[n * 320 + kt * 32 + lq * 8]);
                acc1[0][nt] = __builtin_amdgcn_mfma_f32_16x16x32_bf16(a0, b, acc1[0][nt], 0, 0, 0);
                acc1[1][nt] = __builtin_amdgcn_mfma_f32_16x16x32_bf16(a1, b, acc1[1][nt], 0, 0, 0);
            }
        }
        __syncthreads();

        // ---- hidL transpose into XB (stride 264, cols 0..255) ----
#pragma unroll
        for (int nt = 0; nt < 4; ++nt) {
            int col = wave * 64 + nt * 16 + ln;
            float wb = Wb[col];
#pragma unroll
            for (int mt = 0; mt < 2; ++mt)
#pragma unroll
                for (int r = 0; r < 4; ++r)
                    S.XB[mt * 16 + lq * 4 + r][col] = f2bf(fmaxf(acc1[mt][nt][r] + wb, 0.f));
        }
        __syncthreads();

        // stage 2: hid A-frags cached in registers
        s8v ha0[8], ha1[8];
#pragma unroll
        for (int kt = 0; kt < 8; ++kt) {
            ha0[kt] = frag(&S.XB[ln][kt * 32 + lq * 8]);
            ha1[kt] = frag(&S.XB[16 + ln][kt * 32 + lq * 8]);
        }

        int rt[2][4];
#pragma unroll
        for (int mt = 0; mt < 2; ++mt)
#pragma unroll
            for (int r = 0; r < 4; ++r) rt[mt][r] = S.tgts[mt * 16 + lq * 4 + r];
        float mx[2][4], ls[2][4], tg[2][4]; int am[2][4];
#pragma unroll
        for (int mt = 0; mt < 2; ++mt)
#pragma unroll
            for (int r = 0; r < 4; ++r) { mx[mt][r] = -1e30f; ls[mt][r] = 0.f; tg[mt][r] = 0.f; am[mt][r] = 1 << 30; }

        for (int nt = wave; nt < 50; nt += 4) {
            int n = nt * 16 + ln;
            const unsigned short* wrow = WoT + n * 256;
            f4v a2[2];
            a2[0] = (f4v){0.f, 0.f, 0.f, 0.f}; a2[1] = (f4v){0.f, 0.f, 0.f, 0.f};
#pragma unroll
            for (int kt = 0; kt < 8; ++kt) {
                s8v b = frag(&wrow[kt * 32 + lq * 8]);
                a2[0] = __builtin_amdgcn_mfma_f32_16x16x32_bf16(ha0[kt], b, a2[0], 0, 0, 0);
                a2[1] = __builtin_amdgcn_mfma_f32_16x16x32_bf16(ha1[kt], b, a2[1], 0, 0, 0);
            }
            float bias = Wob[n];
#pragma unroll
            for (int mt = 0; mt < 2; ++mt)
#pragma unroll
                for (int r = 0; r < 4; ++r) {
                    float v = a2[mt][r] + bias;
                    if (n == rt[mt][r]) tg[mt][r] = v;
                    float d = v - mx[mt][r];
                    float e = __expf(-fabsf(d));
                    bool newmax = d > 0.f;
                    ls[mt][r] = fmaf(ls[mt][r], newmax ? e : 1.f, newmax ? 1.f : e);
                    if (newmax) { mx[mt][r] = v; am[mt][r] = n; }
                }
        }

#pragma unroll
        for (int s = 1; s < 16; s <<= 1) {
#pragma unroll
            for (int mt = 0; mt < 2; ++mt)
#pragma unroll
                for (int r = 0; r < 4; ++r) {
                    float mo = __shfl_xor(mx[mt][r], s);
                    float lo = __shfl_xor(ls[mt][r], s);
                    int   ao = __shfl_xor(am[mt][r], s);
                    float to = __shfl_xor(tg[mt][r], s);
                    tg[mt][r] += to;
                    float nm = fmaxf(mx[mt][r], mo);
                    ls[mt][r] = ls[mt][r] * __expf(mx[mt][r] - nm) + lo * __expf(mo - nm);
                    if (mo > mx[mt][r] || (mo == mx[mt][r] && ao < am[mt][r])) am[mt][r] = ao;
                    mx[mt][r] = nm;
                }
        }
        if (ln == 0) {
#pragma unroll
            for (int mt = 0; mt < 2; ++mt)
#pragma unroll
                for (int r = 0; r < 4; ++r) {
                    int row = mt * 16 + lq * 4 + r;
                    S.wred[wave][row][0] = mx[mt][r];
                    S.wred[wave][row][1] = ls[mt][r];
                    S.wred[wave][row][2] = __int_as_float(am[mt][r]);
                    S.wred[wave][row][3] = tg[mt][r];
                }
        }
        __syncthreads();

        float lossv = 0.f, corrv = 0.f;
        if (tid < QG) {
            float m_ = -1e30f, l_ = 0.f, t_ = 0.f; int a_ = 1 << 30;
#pragma unroll
            for (int w = 0; w < 4; ++w) {
                float mo = S.wred[w][tid][0], lo = S.wred[w][tid][1], to = S.wred[w][tid][3];
                int ao = __float_as_int(S.wred[w][tid][2]);
                t_ += to;
                float nm = fmaxf(m_, mo);
                l_ = l_ * __expf(m_ - nm) + lo * __expf(mo - nm);
                if (mo > m_ || (mo == m_ && ao < a_)) a_ = ao;
                m_ = nm;
            }
            lossv = m_ + logf(l_) - t_;
            corrv = (a_ == S.tgts[tid]) ? 1.f : 0.f;
        }
        if (wave == 0) {
            for (int s = 32; s; s >>= 1) {
                lossv += __shfl_down(lossv, s);
                corrv += __shfl_down(corrv, s);
            }
            if (tid == 0) {
                int slot = blockIdx.x & 255;
                atomicAdd(&acc[0 * 256 + slot], lossv);
                atomicAdd(&acc[2 * 256 + slot], corrv);
            }
        }
    } else {
        // ================= P head =================
        PSmem& S = *(PSmem*)smem;
        const int pb = blockIdx.x - 768;
        const int trow = pb >> 4;
        const int b0 = (pb & 15) * PG;
        const int node = (trow == 0) ? 0 : ((trow <= NFWD) ? trow : (TSTEP - trow));

        if (tid < PG) S.widL[tid] = wid[(b0 + tid) * NNODE + node];
        __syncthreads();

        f4v a1[2][4];
#pragma unroll
        for (int mt = 0; mt < 2; ++mt)
#pragma unroll
            for (int nt = 0; nt < 4; ++nt) a1[mt][nt] = (f4v){0.f, 0.f, 0.f, 0.f};

        // ---- chunk 0: emb (kt 0..7) ----
        for (int idx = tid; idx < PG * 32; idx += 256) {
            int m = idx >> 5, c = idx & 31;
            *(int4*)&S.XB[m][c * 8] = *(const int4*)&embB[S.widL[m] * HD + c * 8];
        }
        __syncthreads();
#pragma unroll
        for (int kt = 0; kt < 8; ++kt) {
            s8v a0 = frag(&S.XB[ln][kt * 32 + lq * 8]);
            s8v am_ = frag(&S.XB[16 + ln][kt * 32 + lq * 8]);
#pragma unroll
            for (int nt = 0; nt < 4; ++nt) {
                int n = wave * 64 + nt * 16 + ln;
                s8v b = frag(&UwT[n * 576 + kt * 32 + lq * 8]);
                a1[0][nt] = __builtin_amdgcn_mfma_f32_16x16x32_bf16(a0, b, a1[0][nt], 0, 0, 0);
                a1[1][nt] = __builtin_amdgcn_mfma_f32_16x16x32_bf16(am_, b, a1[1][nt], 0, 0, 0);
            }
        }
        __syncthreads();

        // ---- chunk 1: h (kt 8..15) ----
        if (trow == 0) {
            int4 z = make_int4(0, 0, 0, 0);
            for (int idx = tid; idx < PG * 32; idx += 256) {
                int m = idx >> 5, c = idx & 31;
                *(int4*)&S.XB[m][c * 8] = z;
            }
        } else {
            const unsigned short* hrow = hsb + (size_t)(trow - 1) * NTREE * HD;
            for (int idx = tid; idx < PG * 32; idx += 256) {
                int m = idx >> 5, c = idx & 31;
                *(int4*)&S.XB[m][c * 8] = *(const int4*)&hrow[(b0 + m) * HD + c * 8];
            }
        }
        __syncthreads();
#pragma unroll
        for (int kt = 8; kt < 16; ++kt) {
            s8v a0 = frag(&S.XB[ln][(kt - 8) * 32 + lq * 8]);
            s8v am_ = frag(&S.XB[16 + ln][(kt - 8) * 32 + lq * 8]);
#pragma unroll
            for (int nt = 0; nt < 4; ++nt) {
                int n = wave * 64 + nt * 16 + ln;
                s8v b = frag(&UwT[n * 576 + kt * 32 + lq * 8]);
                a1[0][nt] = __builtin_amdgcn_mfma_f32_16x16x32_bf16(a0, b, a1[0][nt], 0, 0, 0);
                a1[1][nt] = __builtin_amdgcn_mfma_f32_16x16x32_bf16(am_, b, a1[1][nt], 0, 0, 0);
            }
        }
        __syncthreads();

        // ---- chunk 2: tv (kt 16..17) ----
        if (tid < PG * 8) {
            int m = tid >> 3, c = tid & 7;
            *(int4*)&S.XB[m][c * 8] = *(const int4*)&tvB[(b0 + m) * LD + c * 8];
        }
        __syncthreads();
#pragma unroll
        for (int kt = 16; kt < 18; ++kt) {
            s8v a0 = frag(&S.XB[ln][(kt - 16) * 32 + lq * 8]);
            s8v am_ = frag(&S.XB[16 + ln][(kt - 16) * 32 + lq * 8]);
#pragma unroll
            for (int nt = 0; nt < 4; ++nt) {
                int n = wave * 64 + nt * 16 + ln;
                s8v b = frag(&UwT[n * 576 + kt * 32 + lq * 8]);
                a1[0][nt] = __builtin_amdgcn_mfma_f32_16x16x32_bf16(a0, b, a1[0][nt], 0, 0, 0);
                a1[1][nt] = __builtin_amdgcn_mfma_f32_16x16x32_bf16(am_, b, a1[1][nt], 0, 0, 0);
            }
        }

        float part[2][4] = {{0, 0, 0, 0}, {0, 0, 0, 0}};
#pragma unroll
        for (int nt = 0; nt < 4; ++nt) {
            int n = wave * 64 + nt * 16 + ln;
            float ub = Ub[n], us = Usw[n];
#pragma unroll
            for (int mt = 0; mt < 2; ++mt)
#pragma unroll
                for (int r = 0; r < 4; ++r)
                    part[mt][r] += fmaxf(a1[mt][nt][r] + ub, 0.f) * us;
        }
#pragma unroll
        for (int s = 1; s < 16; s <<= 1) {
#pragma unroll
            for (int mt = 0; mt < 2; ++mt)
#pragma unroll
                for (int r = 0; r < 4; ++r)
                    part[mt][r] += __shfl_xor(part[mt][r], s);
        }
        if (ln == 0) {
#pragma unroll
            for (int mt = 0; mt < 2; ++mt)
#pragma unroll
                for (int r = 0; r < 4; ++r)
                    S.wredp[wave][mt * 16 + lq * 4 + r] = part[mt][r];
        }
        __syncthreads();

        float lossv = 0.f, corrv = 0.f;
        if (tid < PG) {
            float p = S.wredp[0][tid] + S.wredp[1][tid] + S.wredp[2][tid] + S.wredp[3][tid] + Usb[0];
            float tgt = (trow < NFWD) ? 1.f : 0.f;
            lossv = fmaxf(p, 0.f) - p * tgt + log1pf(expf(-fabsf(p)));
            corrv = (((p > 0.f) ? 1 : 0) == ((trow < NFWD) ? 1 : 0)) ? 1.f : 0.f;
        }
        if (wave == 0) {
            for (int s = 32; s; s >>= 1) {
                lossv += __shfl_down(lossv, s);
                corrv += __shfl_down(corrv, s);
            }
            if (tid == 0) {
                int slot = blockIdx.x & 255;
                atomicAdd(&acc[1 * 256 + slot], lossv);
                atomicAdd(&acc[3 * 256 + slot], corrv);
            }
        }
    }
}

__global__ void fin_kernel(const float* __restrict__ acc, float* __restrict__ out) {
    const int tid = threadIdx.x;
    const int c = tid >> 6, lane = tid & 63;
    float v = 0.f;
    for (int i = lane; i < 256; i += 64) v += acc[c * 256 + i];
    for (int s = 32; s; s >>= 1) v += __shfl_down(v, s);
    if (lane == 0) {
        const float sc[4] = {1.f / 512.f, 1.f / 512.f, 1.f / 24576.f, 1.f / 48640.f};
        out[c] = v * sc[c];
    }
}

extern "C" void kernel_launch(void* const* d_in, const int* in_sizes, int n_in,
                              void* d_out, int out_size, void* d_ws, size_t ws_size,
                              hipStream_t stream) {
    const int*   wid  = (const int*)  d_in[12];
    const float* tv   = (const float*)d_in[13];
    const float* emb  = (const float*)d_in[14];
    const float* Wz   = (const float*)d_in[15];
    const float* bz   = (const float*)d_in[16];
    const float* Wr   = (const float*)d_in[17];
    const float* Ur   = (const float*)d_in[18];
    const float* br   = (const float*)d_in[19];
    const float* Wh   = (const float*)d_in[20];
    const float* bh   = (const float*)d_in[21];
    const float* Ww   = (const float*)d_in[22];
    const float* Wb   = (const float*)d_in[23];
    const float* Uw   = (const float*)d_in[24];
    const float* Ubias= (const float*)d_in[25];
    const float* Wow  = (const float*)d_in[26];
    const float* Wob  = (const float*)d_in[27];
    const float* Usw  = (const float*)d_in[28];
    const float* Usb  = (const float*)d_in[29];

    char* w = (char*)d_ws;
    float* accb = (float*)w;                                 // 4 KB
    float* xzT  = (float*)(w + 4096);                        // 800*256 f32
    float* xhT  = (float*)(w + 823296);
    float* xrT  = (float*)(w + 1642496);
    unsigned short* WzT2 = (unsigned short*)(w + 2461696);   // [256 n][256 k] bf16
    unsigned short* WhT2 = (unsigned short*)(w + 2592768);
    unsigned short* UrT2 = (unsigned short*)(w + 2723840);
    unsigned short* hsb  = (unsigned short*)(w + 2854912);   // 94*512*256 bf16
    unsigned short* W1T  = (unsigned short*)(w + 27496448);  // [256][320]
    unsigned short* WoT  = (unsigned short*)(w + 27660288);  // [800][256]
    unsigned short* UwT  = (unsigned short*)(w + 28069888);  // [256][576]
    unsigned short* embB = (unsigned short*)(w + 28364800);  // [800][256]
    unsigned short* tvB  = (unsigned short*)(w + 28774400);  // [512][64]

    prep_xproj<<<VOC / PV, 256, 0, stream>>>(emb, Wz, bz, Wh, bh, Wr, br, xzT, xhT, xrT);
    prep_misc<<<3012, 256, 0, stream>>>(Wz, Wh, Ur, Ww, Wow, Uw, emb, tv,
                                        WzT2, WhT2, UrT2, W1T, WoT, UwT,
                                        embB, tvB, accb);
    gru12<<<NTREE / 2, 512, 0, stream>>>(wid, xzT, xhT, xrT, WzT2, WhT2, UrT2, hsb);
    fixup<<<46 * 128, 256, 0, stream>>>(hsb);
    heads<<<768 + 1520, 256, 0, stream>>>(wid, tvB, embB, hsb, W1T, WoT, UwT,
                                          Wb, Wob, Ubias, Usw, Usb, accb);
    fin_kernel<<<1, 256, 0, stream>>>(accb, (float*)d_out);
}

// Round 20
// 373.505 us; speedup vs baseline: 1.3616x; 1.0254x over previous
//
#include <hip/hip_runtime.h>
#include <math.h>

#define NTREE 512
#define NNODE 48
#define HD 256
#define LD 64
#define VOC 800
#define TSTEP 94
#define NFWD 47

typedef __attribute__((ext_vector_type(8))) short s8v;   // 8 bf16 (4 VGPRs)
typedef __attribute__((ext_vector_type(4))) float f4v;   // 4 fp32 acc

// fast device transcendentals (v_exp_f32 + v_rcp_f32), GRU-only
__device__ __forceinline__ float sigm_f(float x) {
    return __builtin_amdgcn_rcpf(1.f + __expf(-x));
}
__device__ __forceinline__ float tanh_f(float x) {
    return 1.f - 2.f * __builtin_amdgcn_rcpf(1.f + __expf(2.f * x));
}

__device__ __forceinline__ float bfu(unsigned short u) {
    union { unsigned int i; float f; } c; c.i = ((unsigned int)u) << 16; return c.f;
}
__device__ __forceinline__ unsigned short f2bf(float f) {
    union { float f; unsigned int u; } c; c.f = f;
    return (unsigned short)((c.u + 0x7fffu + ((c.u >> 16) & 1u)) >> 16);
}
__device__ __forceinline__ s8v frag(const unsigned short* p) {
    union { int4 i; s8v v; } u; u.i = *(const int4*)p; return u.v;
}
__device__ __forceinline__ s8v zfrag() {
    union { int4 i; s8v v; } u; u.i = make_int4(0, 0, 0, 0); return u.v;
}
// LDS-only barrier: global ops (hsb stores, gathers) stay in flight.
__device__ __forceinline__ void bar_lgkm() {
    asm volatile("s_waitcnt lgkmcnt(0)\n\ts_barrier" ::: "memory");
}

// ---------------------------------------------------------------------------
// Precompute x-projections for all 800 vocab words (biases folded in).
// ---------------------------------------------------------------------------
#define PV 8
__global__ __launch_bounds__(256) void prep_xproj(
    const float* __restrict__ emb,
    const float* __restrict__ Wz, const float* __restrict__ bz,
    const float* __restrict__ Wh, const float* __restrict__ bh,
    const float* __restrict__ Wr, const float* __restrict__ br,
    float* __restrict__ xzT, float* __restrict__ xhT, float* __restrict__ xrT)
{
    __shared__ float embL[PV][HD];
    const int j = threadIdx.x;
    const int v0 = blockIdx.x * PV;
    for (int r = 0; r < PV; ++r) embL[r][j] = emb[(v0 + r) * HD + j];
    __syncthreads();

    float az[PV], ah[PV], ar[PV];
#pragma unroll
    for (int r = 0; r < PV; ++r) { az[r] = bz[j]; ah[r] = bh[j]; ar[r] = br[j]; }
    for (int i = 0; i < HD; i += 4) {
        float wz0 = Wz[(i + 0) * HD + j], wz1 = Wz[(i + 1) * HD + j];
        float wz2 = Wz[(i + 2) * HD + j], wz3 = Wz[(i + 3) * HD + j];
        float wh0 = Wh[(i + 0) * HD + j], wh1 = Wh[(i + 1) * HD + j];
        float wh2 = Wh[(i + 2) * HD + j], wh3 = Wh[(i + 3) * HD + j];
        float wr0 = Wr[(i + 0) * HD + j], wr1 = Wr[(i + 1) * HD + j];
        float wr2 = Wr[(i + 2) * HD + j], wr3 = Wr[(i + 3) * HD + j];
#pragma unroll
        for (int r = 0; r < PV; ++r) {
            float4 e = *(const float4*)&embL[r][i];
            az[r] += e.x * wz0 + e.y * wz1 + e.z * wz2 + e.w * wz3;
            ah[r] += e.x * wh0 + e.y * wh1 + e.z * wh2 + e.w * wh3;
            ar[r] += e.x * wr0 + e.y * wr1 + e.z * wr2 + e.w * wr3;
        }
    }
#pragma unroll
    for (int r = 0; r < PV; ++r) {
        xzT[(v0 + r) * HD + j] = az[r];
        xhT[(v0 + r) * HD + j] = ah[r];
        xrT[(v0 + r) * HD + j] = ar[r];
    }
}

// ---------------------------------------------------------------------------
// Fused misc prep: [0,4) init acc; [4,772) tcvt3; [772,2084) tcvtQ;
// [2084, 3012) cvtE  (928 blocks exact).
// ---------------------------------------------------------------------------
__global__ __launch_bounds__(256) void prep_misc(
    const float* __restrict__ Wz, const float* __restrict__ Wh,
    const float* __restrict__ Ur,
    const float* __restrict__ Ww, const float* __restrict__ Wow,
    const float* __restrict__ Uw,
    const float* __restrict__ emb, const float* __restrict__ tv,
    unsigned short* __restrict__ WzT, unsigned short* __restrict__ WhT,
    unsigned short* __restrict__ UrT,
    unsigned short* __restrict__ W1T, unsigned short* __restrict__ WoT,
    unsigned short* __restrict__ UwT,
    unsigned short* __restrict__ embB, unsigned short* __restrict__ tvB,
    float* __restrict__ acc)
{
    int b = blockIdx.x;
    if (b < 4) {
        acc[b * 256 + threadIdx.x] = 0.f;
    } else if (b < 772) {
        int bb = b - 4;
        const int which = bb >> 8, n = bb & 255, k = threadIdx.x;
        const float* src = (which == 0) ? (Wz + HD * HD) : (which == 1) ? (Wh + HD * HD) : Ur;
        unsigned short* dst = (which == 0) ? WzT : (which == 1) ? WhT : UrT;
        dst[n * HD + k] = f2bf(src[k * HD + n]);
    } else if (b < 2084) {
        int bb = b - 772;
        if (bb < 256) {
            for (int k = threadIdx.x; k < 320; k += 256)
                W1T[bb * 320 + k] = f2bf(Ww[k * 256 + bb]);
        } else if (bb < 1056) {
            int n = bb - 256;
            WoT[n * 256 + threadIdx.x] = f2bf(Wow[threadIdx.x * VOC + n]);
        } else {
            int n = bb - 1056;
            for (int k = threadIdx.x; k < 576; k += 256)
                UwT[n * 576 + k] = f2bf(Uw[k * 256 + n]);
        }
    } else {
        int idx = (b - 2084) * 256 + threadIdx.x;
        if (idx < VOC * HD) embB[idx] = f2bf(emb[idx]);
        else {
            int i2 = idx - VOC * HD;
            if (i2 < NTREE * LD) tvB[i2] = f2bf(tv[i2]);
        }
    }
}

// ---------------------------------------------------------------------------
// GRU v12 (champion): fwd+backtrack chains in parallel, 47 steps, deferred
// additive coupling (now applied inside the P-head staging). UNCHANGED.
// ---------------------------------------------------------------------------
#define ASTR 264
__global__ __launch_bounds__(512, 2) void gru12(
    const int* __restrict__ wid,
    const float* __restrict__ xzT, const float* __restrict__ xhT,
    const float* __restrict__ xrT,
    const unsigned short* __restrict__ WzT, const unsigned short* __restrict__ WhT,
    const unsigned short* __restrict__ UrT,
    unsigned short* __restrict__ hsb)
{
    __shared__ unsigned short urL[16 * 8 * 64 * 8];   // 128 KB [tile][kt][lane][8]
    __shared__ unsigned short mBL[2][4][ASTR], armBL[2][4][ASTR];
    __shared__ int widL[2][NNODE];

    const int tid = threadIdx.x;
    const int wave = tid >> 6, lane = tid & 63;
    const int lq = lane >> 4, ln = lane & 15;
    const int b0 = blockIdx.x * 2;
    const int T0 = 2 * wave, T1 = T0 + 1;
    const int ftree = lane >> 5;
    const int fcol  = wave * 32 + (lane & 31);
    const int srcl  = lane & 15;
    const bool hi16 = (lane & 16) != 0;
    const bool hi32 = (lane & 32) != 0;

    if (tid < 2 * NNODE) widL[tid / NNODE][tid % NNODE] =
        wid[(b0 + tid / NNODE) * NNODE + (tid % NNODE)];

#pragma unroll
    for (int s = 0; s < 16; ++s) {
        *(int4*)&urL[((s * 8 + wave) * 64 + lane) * 8] =
            *(const int4*)&UrT[(s * 16 + ln) * HD + wave * 32 + lq * 8];
    }

    s8v wz0[8], wz1[8], wh0[8], wh1[8];
#pragma unroll
    for (int kt = 0; kt < 8; ++kt) {
        const int ko = kt * 32 + lq * 8;
        wz0[kt] = frag(&WzT[(T0 * 16 + ln) * HD + ko]);
        wz1[kt] = frag(&WzT[(T1 * 16 + ln) * HD + ko]);
        wh0[kt] = frag(&WhT[(T0 * 16 + ln) * HD + ko]);
        wh1[kt] = frag(&WhT[(T1 * 16 + ln) * HD + ko]);
    }
    __syncthreads();   // widL + urL visible

    // per-lane state for 2 chains: [0]=forward (row s), [1]=backtrack (row 47+s)
    float cxz[2], cxh[2], cxr[2], me2[2] = {0.f, 0.f};
    float nxz[2] = {0.f, 0.f}, nxh[2] = {0.f, 0.f}, nxr[2] = {0.f, 0.f};
    {   // s=0: fwd src=0,dst=1; bt src=47,dst=46
        cxz[0] = xzT[widL[ftree][0] * HD + fcol];
        cxh[0] = xhT[widL[ftree][0] * HD + fcol];
        cxr[0] = xrT[widL[ftree][1] * HD + fcol];
        cxz[1] = xzT[widL[ftree][47] * HD + fcol];
        cxh[1] = xhT[widL[ftree][47] * HD + fcol];
        cxr[1] = xrT[widL[ftree][46] * HD + fcol];
    }

    for (int s = 0; s < NFWD; ++s) {
        const int par = s & 1, nxt = par ^ 1;
        const bool hp = (s != 0);

        // ---- prefetch for s+1 (registers only) ----
        {
            const int sn = s + 1;
            if (sn < NFWD) {
                const int un = NFWD - sn;
                nxz[0] = xzT[widL[ftree][sn] * HD + fcol];
                nxh[0] = xhT[widL[ftree][sn] * HD + fcol];
                nxr[0] = xrT[widL[ftree][sn + 1] * HD + fcol];
                nxz[1] = xzT[widL[ftree][un] * HD + fcol];
                nxh[1] = xhT[widL[ftree][un] * HD + fcol];
                nxr[1] = xrT[widL[ftree][un - 1] * HD + fcol];
            }
        }

        // ---- phase A MFMA + shuffle redistribute: az, ah for both chains ----
        float az[2] = {0.f, 0.f}, ah[2] = {0.f, 0.f};
        if (hp) {
            f4v cz0 = (f4v){0.f,0.f,0.f,0.f}, cz1 = cz0, ch0 = cz0, ch1 = cz0;
#pragma unroll
            for (int kt = 0; kt < 8; ++kt) {
                const int ko = kt * 32 + lq * 8;
                s8v am = (ln < 4) ? frag(&mBL[par][ln][ko]) : zfrag();
                s8v aa = (ln < 4) ? frag(&armBL[par][ln][ko]) : zfrag();
                cz0 = __builtin_amdgcn_mfma_f32_16x16x32_bf16(am, wz0[kt], cz0, 0, 0, 0);
                cz1 = __builtin_amdgcn_mfma_f32_16x16x32_bf16(am, wz1[kt], cz1, 0, 0, 0);
                ch0 = __builtin_amdgcn_mfma_f32_16x16x32_bf16(aa, wh0[kt], ch0, 0, 0, 0);
                ch1 = __builtin_amdgcn_mfma_f32_16x16x32_bf16(aa, wh1[kt], ch1, 0, 0, 0);
            }
            // C rows 0-3 = chains (regs 0-3 of lq==0 lanes). fwd=reg ftree, bt=reg 2+ftree.
            float f0 = __shfl(cz0[0], srcl), f1 = __shfl(cz0[1], srcl);
            float g0 = __shfl(cz1[0], srcl), g1 = __shfl(cz1[1], srcl);
            az[0] = hi16 ? (hi32 ? g1 : g0) : (hi32 ? f1 : f0);
            float f2 = __shfl(cz0[2], srcl), f3 = __shfl(cz0[3], srcl);
            float g2 = __shfl(cz1[2], srcl), g3 = __shfl(cz1[3], srcl);
            az[1] = hi16 ? (hi32 ? g3 : g2) : (hi32 ? f3 : f2);
            float h0 = __shfl(ch0[0], srcl), h1 = __shfl(ch0[1], srcl);
            float i0 = __shfl(ch1[0], srcl), i1 = __shfl(ch1[1], srcl);
            ah[0] = hi16 ? (hi32 ? i1 : i0) : (hi32 ? h1 : h0);
            float h2 = __shfl(ch0[2], srcl), h3 = __shfl(ch0[3], srcl);
            float i2 = __shfl(ch1[2], srcl), i3 = __shfl(ch1[3], srcl);
            ah[1] = hi16 ? (hi32 ? i3 : i2) : (hi32 ? h3 : h2);
        }

        // ---- finalize A (per-lane, 2 chains) ----
        {
#pragma unroll
            for (int c = 0; c < 2; ++c) {
                float azv = cxz[c], ahv = cxh[c], sold = 0.f;
                if (hp) { azv += az[c]; ahv += ah[c]; sold = me2[c]; }
                float z = sigm_f(azv), mt = tanh_f(ahv);
                float me = sold + z * (mt - sold);
                const int row = (c == 0) ? s : (NFWD + s);
                hsb[((size_t)row * NTREE + b0 + ftree) * HD + fcol] = f2bf(me);
                mBL[nxt][c * 2 + ftree][fcol] = f2bf(me);
                me2[c] = me;
            }
        }
        bar_lgkm();

        // ---- phase B MFMA + shuffle: ar = m_e @ Ur ----
        {
            f4v cr0 = (f4v){0.f,0.f,0.f,0.f}, cr1 = cr0;
#pragma unroll
            for (int kt = 0; kt < 8; ++kt) {
                const int ko = kt * 32 + lq * 8;
                s8v a = (ln < 4) ? frag(&mBL[nxt][ln][ko]) : zfrag();
                s8v b0f = frag(&urL[((T0 * 8 + kt) * 64 + lane) * 8]);
                s8v b1f = frag(&urL[((T1 * 8 + kt) * 64 + lane) * 8]);
                cr0 = __builtin_amdgcn_mfma_f32_16x16x32_bf16(a, b0f, cr0, 0, 0, 0);
                cr1 = __builtin_amdgcn_mfma_f32_16x16x32_bf16(a, b1f, cr1, 0, 0, 0);
            }
            float f0 = __shfl(cr0[0], srcl), f1 = __shfl(cr0[1], srcl);
            float g0 = __shfl(cr1[0], srcl), g1 = __shfl(cr1[1], srcl);
            float ar0 = hi16 ? (hi32 ? g1 : g0) : (hi32 ? f1 : f0);
            float f2 = __shfl(cr0[2], srcl), f3 = __shfl(cr0[3], srcl);
            float g2 = __shfl(cr1[2], srcl), g3 = __shfl(cr1[3], srcl);
            float ar1 = hi16 ? (hi32 ? g3 : g2) : (hi32 ? f3 : f2);
            armBL[nxt][0 * 2 + ftree][fcol] = f2bf(sigm_f(cxr[0] + ar0) * me2[0]);
            armBL[nxt][1 * 2 + ftree][fcol] = f2bf(sigm_f(cxr[1] + ar1) * me2[1]);
#pragma unroll
            for (int c = 0; c < 2; ++c) {
                cxz[c] = nxz[c]; cxh[c] = nxh[c]; cxr[c] = nxr[c];
            }
        }
        bar_lgkm();
    }
}

// ---------------------------------------------------------------------------
// Fused heads v4: fixup folded into P-head h-staging (rows 47..92 get
// + hs_fwd[93-trow] at stage time, bit-identical rounding to the old fixup
// kernel). Q unchanged (reads forward rows only). Chunked single-buffer LDS.
// ---------------------------------------------------------------------------
#define QG 32
#define PG 32
#define XSTR 264
struct QSmem {
    unsigned short XB[QG][XSTR];
    int tgts[QG];
    float wred[4][QG][4];
};
struct PSmem {
    unsigned short XB[PG][XSTR];
    int widL[PG];
    float wredp[4][PG];
};

__global__ __launch_bounds__(256) void heads(
    const int* __restrict__ wid,
    const unsigned short* __restrict__ tvB,
    const unsigned short* __restrict__ embB,
    const unsigned short* __restrict__ hsb,
    const unsigned short* __restrict__ W1T,
    const unsigned short* __restrict__ WoT,
    const unsigned short* __restrict__ UwT,
    const float* __restrict__ Wb, const float* __restrict__ Wob,
    const float* __restrict__ Ub,
    const float* __restrict__ Usw, const float* __restrict__ Usb,
    float* __restrict__ acc)
{
    __shared__ __align__(16) char smem[sizeof(QSmem) > sizeof(PSmem) ? sizeof(QSmem) : sizeof(PSmem)];
    const int tid = threadIdx.x;
    const int wave = tid >> 6, lane = tid & 63;
    const int lq = lane >> 4, ln = lane & 15;

    if (blockIdx.x < 768) {
        // ================= Q head =================
        QSmem& S = *(QSmem*)smem;
        const int trow = blockIdx.x >> 4;
        const int b0 = (blockIdx.x & 15) * QG;

        if (tid < QG) S.tgts[tid] = wid[(b0 + tid) * NNODE + trow];

        // ---- chunk 0: h rows (kt 0..7) ----
        if (trow == 0) {
            int4 z = make_int4(0, 0, 0, 0);
            for (int idx = tid; idx < QG * 32; idx += 256) {
                int m = idx >> 5, c = idx & 31;
                *(int4*)&S.XB[m][c * 8] = z;
            }
        } else {
            const unsigned short* hrow = hsb + (size_t)(trow - 1) * NTREE * HD;
            for (int idx = tid; idx < QG * 32; idx += 256) {
                int m = idx >> 5, c = idx & 31;
                *(int4*)&S.XB[m][c * 8] = *(const int4*)&hrow[(b0 + m) * HD + c * 8];
            }
        }
        __syncthreads();

        f4v acc1[2][4];
#pragma unroll
        for (int mt = 0; mt < 2; ++mt)
#pragma unroll
            for (int nt = 0; nt < 4; ++nt) acc1[mt][nt] = (f4v){0.f, 0.f, 0.f, 0.f};
#pragma unroll
        for (int kt = 0; kt < 8; ++kt) {
            s8v a0 = frag(&S.XB[ln][kt * 32 + lq * 8]);
            s8v a1 = frag(&S.XB[16 + ln][kt * 32 + lq * 8]);
#pragma unroll
            for (int nt = 0; nt < 4; ++nt) {
                int n = wave * 64 + nt * 16 + ln;
                s8v b = frag(&W1T[n * 320 + kt * 32 + lq * 8]);
                acc1[0][nt] = __builtin_amdgcn_mfma_f32_16x16x32_bf16(a0, b, acc1[0][nt], 0, 0, 0);
                acc1[1][nt] = __builtin_amdgcn_mfma_f32_16x16x32_bf16(a1, b, acc1[1][nt], 0, 0, 0);
            }
        }
        __syncthreads();

        // ---- chunk 1: tv (kt 8..9) ----
        if (tid < QG * 8) {
            int m = tid >> 3, c = tid & 7;
            *(int4*)&S.XB[m][c * 8] = *(const int4*)&tvB[(b0 + m) * LD + c * 8];
        }
        __syncthreads();
#pragma unroll
        for (int kt = 8; kt < 10; ++kt) {
            s8v a0 = frag(&S.XB[ln][(kt - 8) * 32 + lq * 8]);
            s8v a1 = frag(&S.XB[16 + ln][(kt - 8) * 32 + lq * 8]);
#pragma unroll
            for (int nt = 0; nt < 4; ++nt) {
                int n = wave * 64 + nt * 16 + ln;
                s8v b = frag(&W1T[n * 320 + kt * 32 + lq * 8]);
                acc1[0][nt] = __builtin_amdgcn_mfma_f32_16x16x32_bf16(a0, b, acc1[0][nt], 0, 0, 0);
                acc1[1][nt] = __builtin_amdgcn_mfma_f32_16x16x32_bf16(a1, b, acc1[1][nt], 0, 0, 0);
            }
        }
        __syncthreads();

        // ---- hidL transpose into XB (stride 264, cols 0..255) ----
#pragma unroll
        for (int nt = 0; nt < 4; ++nt) {
            int col = wave * 64 + nt * 16 + ln;
            float wb = Wb[col];
#pragma unroll
            for (int mt = 0; mt < 2; ++mt)
#pragma unroll
                for (int r = 0; r < 4; ++r)
                    S.XB[mt * 16 + lq * 4 + r][col] = f2bf(fmaxf(acc1[mt][nt][r] + wb, 0.f));
        }
        __syncthreads();

        // stage 2: hid A-frags cached in registers
        s8v ha0[8], ha1[8];
#pragma unroll
        for (int kt = 0; kt < 8; ++kt) {
            ha0[kt] = frag(&S.XB[ln][kt * 32 + lq * 8]);
            ha1[kt] = frag(&S.XB[16 + ln][kt * 32 + lq * 8]);
        }

        int rt[2][4];
#pragma unroll
        for (int mt = 0; mt < 2; ++mt)
#pragma unroll
            for (int r = 0; r < 4; ++r) rt[mt][r] = S.tgts[mt * 16 + lq * 4 + r];
        float mx[2][4], ls[2][4], tg[2][4]; int am[2][4];
#pragma unroll
        for (int mt = 0; mt < 2; ++mt)
#pragma unroll
            for (int r = 0; r < 4; ++r) { mx[mt][r] = -1e30f; ls[mt][r] = 0.f; tg[mt][r] = 0.f; am[mt][r] = 1 << 30; }

        for (int nt = wave; nt < 50; nt += 4) {
            int n = nt * 16 + ln;
            const unsigned short* wrow = WoT + n * 256;
            f4v a2[2];
            a2[0] = (f4v){0.f, 0.f, 0.f, 0.f}; a2[1] = (f4v){0.f, 0.f, 0.f, 0.f};
#pragma unroll
            for (int kt = 0; kt < 8; ++kt) {
                s8v b = frag(&wrow[kt * 32 + lq * 8]);
                a2[0] = __builtin_amdgcn_mfma_f32_16x16x32_bf16(ha0[kt], b, a2[0], 0, 0, 0);
                a2[1] = __builtin_amdgcn_mfma_f32_16x16x32_bf16(ha1[kt], b, a2[1], 0, 0, 0);
            }
            float bias = Wob[n];
#pragma unroll
            for (int mt = 0; mt < 2; ++mt)
#pragma unroll
                for (int r = 0; r < 4; ++r) {
                    float v = a2[mt][r] + bias;
                    if (n == rt[mt][r]) tg[mt][r] = v;
                    float d = v - mx[mt][r];
                    float e = __expf(-fabsf(d));
                    bool newmax = d > 0.f;
                    ls[mt][r] = fmaf(ls[mt][r], newmax ? e : 1.f, newmax ? 1.f : e);
                    if (newmax) { mx[mt][r] = v; am[mt][r] = n; }
                }
        }

#pragma unroll
        for (int s = 1; s < 16; s <<= 1) {
#pragma unroll
            for (int mt = 0; mt < 2; ++mt)
#pragma unroll
                for (int r = 0; r < 4; ++r) {
                    float mo = __shfl_xor(mx[mt][r], s);
                    float lo = __shfl_xor(ls[mt][r], s);
                    int   ao = __shfl_xor(am[mt][r], s);
                    float to = __shfl_xor(tg[mt][r], s);
                    tg[mt][r] += to;
                    float nm = fmaxf(mx[mt][r], mo);
                    ls[mt][r] = ls[mt][r] * __expf(mx[mt][r] - nm) + lo * __expf(mo - nm);
                    if (mo > mx[mt][r] || (mo == mx[mt][r] && ao < am[mt][r])) am[mt][r] = ao;
                    mx[mt][r] = nm;
                }
        }
        if (ln == 0) {
#pragma unroll
            for (int mt = 0; mt < 2; ++mt)
#pragma unroll
                for (int r = 0; r < 4; ++r) {
                    int row = mt * 16 + lq * 4 + r;
                    S.wred[wave][row][0] = mx[mt][r];
                    S.wred[wave][row][1] = ls[mt][r];
                    S.wred[wave][row][2] = __int_as_float(am[mt][r]);
                    S.wred[wave][row][3] = tg[mt][r];
                }
        }
        __syncthreads();

        float lossv = 0.f, corrv = 0.f;
        if (tid < QG) {
            float m_ = -1e30f, l_ = 0.f, t_ = 0.f; int a_ = 1 << 30;
#pragma unroll
            for (int w = 0; w < 4; ++w) {
                float mo = S.wred[w][tid][0], lo = S.wred[w][tid][1], to = S.wred[w][tid][3];
                int ao = __float_as_int(S.wred[w][tid][2]);
                t_ += to;
                float nm = fmaxf(m_, mo);
                l_ = l_ * __expf(m_ - nm) + lo * __expf(mo - nm);
                if (mo > m_ || (mo == m_ && ao < a_)) a_ = ao;
                m_ = nm;
            }
            lossv = m_ + logf(l_) - t_;
            corrv = (a_ == S.tgts[tid]) ? 1.f : 0.f;
        }
        if (wave == 0) {
            for (int s = 32; s; s >>= 1) {
                lossv += __shfl_down(lossv, s);
                corrv += __shfl_down(corrv, s);
            }
            if (tid == 0) {
                int slot = blockIdx.x & 255;
                atomicAdd(&acc[0 * 256 + slot], lossv);
                atomicAdd(&acc[2 * 256 + slot], corrv);
            }
        }
    } else {
        // ================= P head =================
        PSmem& S = *(PSmem*)smem;
        const int pb = blockIdx.x - 768;
        const int trow = pb >> 4;
        const int b0 = (pb & 15) * PG;
        const int node = (trow == 0) ? 0 : ((trow <= NFWD) ? trow : (TSTEP - trow));

        if (tid < PG) S.widL[tid] = wid[(b0 + tid) * NNODE + node];
        __syncthreads();

        f4v a1[2][4];
#pragma unroll
        for (int mt = 0; mt < 2; ++mt)
#pragma unroll
            for (int nt = 0; nt < 4; ++nt) a1[mt][nt] = (f4v){0.f, 0.f, 0.f, 0.f};

        // ---- chunk 0: emb (kt 0..7) ----
        for (int idx = tid; idx < PG * 32; idx += 256) {
            int m = idx >> 5, c = idx & 31;
            *(int4*)&S.XB[m][c * 8] = *(const int4*)&embB[S.widL[m] * HD + c * 8];
        }
        __syncthreads();
#pragma unroll
        for (int kt = 0; kt < 8; ++kt) {
            s8v a0 = frag(&S.XB[ln][kt * 32 + lq * 8]);
            s8v am_ = frag(&S.XB[16 + ln][kt * 32 + lq * 8]);
#pragma unroll
            for (int nt = 0; nt < 4; ++nt) {
                int n = wave * 64 + nt * 16 + ln;
                s8v b = frag(&UwT[n * 576 + kt * 32 + lq * 8]);
                a1[0][nt] = __builtin_amdgcn_mfma_f32_16x16x32_bf16(a0, b, a1[0][nt], 0, 0, 0);
                a1[1][nt] = __builtin_amdgcn_mfma_f32_16x16x32_bf16(am_, b, a1[1][nt], 0, 0, 0);
            }
        }
        __syncthreads();

        // ---- chunk 1: h (kt 8..15); rows 47..92 get the deferred fwd add ----
        if (trow == 0) {
            int4 z = make_int4(0, 0, 0, 0);
            for (int idx = tid; idx < PG * 32; idx += 256) {
                int m = idx >> 5, c = idx & 31;
                *(int4*)&S.XB[m][c * 8] = z;
            }
        } else if (trow <= NFWD || trow == TSTEP) {
            // rows 0..46 (forward) and row 93 (raw backtrack, v=0): no add
            const unsigned short* hrow = hsb + (size_t)(trow - 1) * NTREE * HD;
            for (int idx = tid; idx < PG * 32; idx += 256) {
                int m = idx >> 5, c = idx & 31;
                *(int4*)&S.XB[m][c * 8] = *(const int4*)&hrow[(b0 + m) * HD + c * 8];
            }
        } else {
            // trow in 48..93 -> row trow-1 in 47..92: h = m_bt + hs_fwd[93-trow]
            const unsigned short* hrow = hsb + (size_t)(trow - 1) * NTREE * HD;
            const unsigned short* frow = hsb + (size_t)(93 - trow) * NTREE * HD;
            for (int idx = tid; idx < PG * 32; idx += 256) {
                int m = idx >> 5, c = idx & 31;
                ushort4 a = *(const ushort4*)&hrow[(b0 + m) * HD + c * 8];
                ushort4 b = *(const ushort4*)&frow[(b0 + m) * HD + c * 8];
                ushort4 a2 = *(const ushort4*)&hrow[(b0 + m) * HD + c * 8 + 4];
                ushort4 b2 = *(const ushort4*)&frow[(b0 + m) * HD + c * 8 + 4];
                ushort4 o, o2;
                o.x  = f2bf(bfu(a.x)  + bfu(b.x));
                o.y  = f2bf(bfu(a.y)  + bfu(b.y));
                o.z  = f2bf(bfu(a.z)  + bfu(b.z));
                o.w  = f2bf(bfu(a.w)  + bfu(b.w));
                o2.x = f2bf(bfu(a2.x) + bfu(b2.x));
                o2.y = f2bf(bfu(a2.y) + bfu(b2.y));
                o2.z = f2bf(bfu(a2.z) + bfu(b2.z));
                o2.w = f2bf(bfu(a2.w) + bfu(b2.w));
                *(ushort4*)&S.XB[m][c * 8] = o;
                *(ushort4*)&S.XB[m][c * 8 + 4] = o2;
            }
        }
        __syncthreads();
#pragma unroll
        for (int kt = 8; kt < 16; ++kt) {
            s8v a0 = frag(&S.XB[ln][(kt - 8) * 32 + lq * 8]);
            s8v am_ = frag(&S.XB[16 + ln][(kt - 8) * 32 + lq * 8]);
#pragma unroll
            for (int nt = 0; nt < 4; ++nt) {
                int n = wave * 64 + nt * 16 + ln;
                s8v b = frag(&UwT[n * 576 + kt * 32 + lq * 8]);
                a1[0][nt] = __builtin_amdgcn_mfma_f32_16x16x32_bf16(a0, b, a1[0][nt], 0, 0, 0);
                a1[1][nt] = __builtin_amdgcn_mfma_f32_16x16x32_bf16(am_, b, a1[1][nt], 0, 0, 0);
            }
        }
        __syncthreads();

        // ---- chunk 2: tv (kt 16..17) ----
        if (tid < PG * 8) {
            int m = tid >> 3, c = tid & 7;
            *(int4*)&S.XB[m][c * 8] = *(const int4*)&tvB[(b0 + m) * LD + c * 8];
        }
        __syncthreads();
#pragma unroll
        for (int kt = 16; kt < 18; ++kt) {
            s8v a0 = frag(&S.XB[ln][(kt - 16) * 32 + lq * 8]);
            s8v am_ = frag(&S.XB[16 + ln][(kt - 16) * 32 + lq * 8]);
#pragma unroll
            for (int nt = 0; nt < 4; ++nt) {
                int n = wave * 64 + nt * 16 + ln;
                s8v b = frag(&UwT[n * 576 + kt * 32 + lq * 8]);
                a1[0][nt] = __builtin_amdgcn_mfma_f32_16x16x32_bf16(a0, b, a1[0][nt], 0, 0, 0);
                a1[1][nt] = __builtin_amdgcn_mfma_f32_16x16x32_bf16(am_, b, a1[1][nt], 0, 0, 0);
            }
        }

        float part[2][4] = {{0, 0, 0, 0}, {0, 0, 0, 0}};
#pragma unroll
        for (int nt = 0; nt < 4; ++nt) {
            int n = wave * 64 + nt * 16 + ln;
            float ub = Ub[n], us = Usw[n];
#pragma unroll
            for (int mt = 0; mt < 2; ++mt)
#pragma unroll
                for (int r = 0; r < 4; ++r)
                    part[mt][r] += fmaxf(a1[mt][nt][r] + ub, 0.f) * us;
        }
#pragma unroll
        for (int s = 1; s < 16; s <<= 1) {
#pragma unroll
            for (int mt = 0; mt < 2; ++mt)
#pragma unroll
                for (int r = 0; r < 4; ++r)
                    part[mt][r] += __shfl_xor(part[mt][r], s);
        }
        if (ln == 0) {
#pragma unroll
            for (int mt = 0; mt < 2; ++mt)
#pragma unroll
                for (int r = 0; r < 4; ++r)
                    S.wredp[wave][mt * 16 + lq * 4 + r] = part[mt][r];
        }
        __syncthreads();

        float lossv = 0.f, corrv = 0.f;
        if (tid < PG) {
            float p = S.wredp[0][tid] + S.wredp[1][tid] + S.wredp[2][tid] + S.wredp[3][tid] + Usb[0];
            float tgt = (trow < NFWD) ? 1.f : 0.f;
            lossv = fmaxf(p, 0.f) - p * tgt + log1pf(expf(-fabsf(p)));
            corrv = (((p > 0.f) ? 1 : 0) == ((trow < NFWD) ? 1 : 0)) ? 1.f : 0.f;
        }
        if (wave == 0) {
            for (int s = 32; s; s >>= 1) {
                lossv += __shfl_down(lossv, s);
                corrv += __shfl_down(corrv, s);
            }
            if (tid == 0) {
                int slot = blockIdx.x & 255;
                atomicAdd(&acc[1 * 256 + slot], lossv);
                atomicAdd(&acc[3 * 256 + slot], corrv);
            }
        }
    }
}

__global__ void fin_kernel(const float* __restrict__ acc, float* __restrict__ out) {
    const int tid = threadIdx.x;
    const int c = tid >> 6, lane = tid & 63;
    float v = 0.f;
    for (int i = lane; i < 256; i += 64) v += acc[c * 256 + i];
    for (int s = 32; s; s >>= 1) v += __shfl_down(v, s);
    if (lane == 0) {
        const float sc[4] = {1.f / 512.f, 1.f / 512.f, 1.f / 24576.f, 1.f / 48640.f};
        out[c] = v * sc[c];
    }
}

extern "C" void kernel_launch(void* const* d_in, const int* in_sizes, int n_in,
                              void* d_out, int out_size, void* d_ws, size_t ws_size,
                              hipStream_t stream) {
    const int*   wid  = (const int*)  d_in[12];
    const float* tv   = (const float*)d_in[13];
    const float* emb  = (const float*)d_in[14];
    const float* Wz   = (const float*)d_in[15];
    const float* bz   = (const float*)d_in[16];
    const float* Wr   = (const float*)d_in[17];
    const float* Ur   = (const float*)d_in[18];
    const float* br   = (const float*)d_in[19];
    const float* Wh   = (const float*)d_in[20];
    const float* bh   = (const float*)d_in[21];
    const float* Ww   = (const float*)d_in[22];
    const float* Wb   = (const float*)d_in[23];
    const float* Uw   = (const float*)d_in[24];
    const float* Ubias= (const float*)d_in[25];
    const float* Wow  = (const float*)d_in[26];
    const float* Wob  = (const float*)d_in[27];
    const float* Usw  = (const float*)d_in[28];
    const float* Usb  = (const float*)d_in[29];

    char* w = (char*)d_ws;
    float* accb = (float*)w;                                 // 4 KB
    float* xzT  = (float*)(w + 4096);                        // 800*256 f32
    float* xhT  = (float*)(w + 823296);
    float* xrT  = (float*)(w + 1642496);
    unsigned short* WzT2 = (unsigned short*)(w + 2461696);   // [256 n][256 k] bf16
    unsigned short* WhT2 = (unsigned short*)(w + 2592768);
    unsigned short* UrT2 = (unsigned short*)(w + 2723840);
    unsigned short* hsb  = (unsigned short*)(w + 2854912);   // 94*512*256 bf16
    unsigned short* W1T  = (unsigned short*)(w + 27496448);  // [256][320]
    unsigned short* WoT  = (unsigned short*)(w + 27660288);  // [800][256]
    unsigned short* UwT  = (unsigned short*)(w + 28069888);  // [256][576]
    unsigned short* embB = (unsigned short*)(w + 28364800);  // [800][256]
    unsigned short* tvB  = (unsigned short*)(w + 28774400);  // [512][64]

    prep_xproj<<<VOC / PV, 256, 0, stream>>>(emb, Wz, bz, Wh, bh, Wr, br, xzT, xhT, xrT);
    prep_misc<<<3012, 256, 0, stream>>>(Wz, Wh, Ur, Ww, Wow, Uw, emb, tv,
                                        WzT2, WhT2, UrT2, W1T, WoT, UwT,
                                        embB, tvB, accb);
    gru12<<<NTREE / 2, 512, 0, stream>>>(wid, xzT, xhT, xrT, WzT2, WhT2, UrT2, hsb);
    heads<<<768 + 1520, 256, 0, stream>>>(wid, tvB, embB, hsb, W1T, WoT, UwT,
                                          Wb, Wob, Ubias, Usw, Usb, accb);
    fin_kernel<<<1, 256, 0, stream>>>(accb, (float*)d_out);
}